// Round 2
// baseline (1438.903 us; speedup 1.0000x reference)
//
#include <hip/hip_runtime.h>
#include <math.h>

#define TPB 256
#define NEG_SLOPE 0.2f
#define COS_EPS 1e-8f
#define NH 6

// ---------- helpers ----------
__device__ inline unsigned fenc(float f) {
  unsigned u = __float_as_uint(f);
  return u ^ ((unsigned)((int)u >> 31) | 0x80000000u);
}
__device__ inline float fdec(unsigned k) {
  unsigned u = (k & 0x80000000u) ? (k ^ 0x80000000u) : ~k;
  return __uint_as_float(u);
}
__device__ inline float wave_sum64(float v) {
  #pragma unroll
  for (int off = 32; off > 0; off >>= 1) v += __shfl_down(v, off);
  return __shfl(v, 0);
}

#define GS_LOOP(i, total) \
  for (long i = (long)blockIdx.x * blockDim.x + threadIdx.x; i < (total); \
       i += (long)gridDim.x * blockDim.x)

// ---------- tiny utility kernels ----------
__global__ void k_fill(float* p, float v, long n) { GS_LOOP(i, n) p[i] = v; }

// deg accumulate: deg[dst[e]] += 1  (deg pre-filled with 1.0 to account for
// the extra self-loop _gcn concatenates; input dst already contains one loop)
__global__ void k_deg(const int* __restrict__ dst, float* __restrict__ deg, long en) {
  GS_LOOP(e, en) atomicAdd(&deg[dst[e]], 1.0f);
}
__global__ void k_dinv(float* __restrict__ deg, long n) {
  GS_LOOP(i, n) deg[i] = rsqrtf(fmaxf(deg[i], 1e-12f));
}

// ---------- GEMM: out[n][Mtot] = A[n][64] @ W[64][Mtot], 64-col tile per blockIdx.y
__global__ void k_gemm64(const float* __restrict__ A, const float* __restrict__ W,
                         float* __restrict__ out, int n, int Mtot) {
  __shared__ float Wl[64 * 64];
  const int col0 = blockIdx.y * 64;
  for (int i = threadIdx.x; i < 4096; i += blockDim.x)
    Wl[i] = W[(i >> 6) * Mtot + col0 + (i & 63)];
  __syncthreads();
  const int lane = threadIdx.x & 63;
  const int wv   = threadIdx.x >> 6;
  const int wpb  = blockDim.x >> 6;
  for (int r = blockIdx.x * wpb + wv; r < n; r += gridDim.x * wpb) {
    float xv  = A[(long)r * 64 + lane];
    float acc = 0.f;
    #pragma unroll
    for (int k = 0; k < 64; ++k)
      acc = fmaf(__shfl(xv, k), Wl[k * 64 + lane], acc);
    out[(long)r * Mtot + col0 + lane] = acc;
  }
}

// xpj init: bias + the extra self-loop contribution (norm = dinv[i]^2)
__global__ void k_xpj_init(const float* __restrict__ h, const float* __restrict__ dinv,
                           const float* __restrict__ bg, float* __restrict__ xpj, long n) {
  GS_LOOP(idx, n * 64) {
    long i = idx >> 6; int c = idx & 63;
    float di = dinv[i];
    xpj[idx] = bg[c] + h[idx] * di * di;
  }
}

// GCN aggregate over the EN input pairs (includes one self-loop per node)
__global__ void k_gcn_agg(const int* __restrict__ src, const int* __restrict__ dst,
                          const float* __restrict__ h, const float* __restrict__ dinv,
                          float* __restrict__ xpj, long en) {
  GS_LOOP(idx, en * 64) {
    long e = idx >> 6; int c = idx & 63;
    int s = src[e], d = dst[e];
    float nrm = dinv[s] * dinv[d];
    atomicAdd(&xpj[(long)d * 64 + c], h[(long)s * 64 + c] * nrm);
  }
}

// per-channel segment max: hmk[d][h][c] = max over edges of h2[s][h][c] (uint keys)
__global__ void k_hmax(const int* __restrict__ ss, const int* __restrict__ sd,
                       const float* __restrict__ h2, unsigned* __restrict__ hmk, long en) {
  GS_LOOP(idx, en * 64) {
    long e = idx >> 6; int c = idx & 63;
    long s = ss[e], d = sd[e];
    #pragma unroll
    for (int h = 0; h < NH; ++h) {
      unsigned k = fenc(h2[s * 384 + h * 64 + c]);
      atomicMax(&hmk[d * 384 + h * 64 + c], k);
    }
  }
}

// per (node,head): salpha = h2[n,h,:]·att_i[h,:]; dalpha = hmax[n,h,:]·att_j[h,:]
__global__ void k_nodedots(const float* __restrict__ h2, const unsigned* __restrict__ hmk,
                           const float* __restrict__ att,
                           float* __restrict__ sal, float* __restrict__ dal, long n) {
  const int lane = threadIdx.x & 63;
  const long wid = ((long)blockIdx.x * blockDim.x + threadIdx.x) >> 6;
  const long nw  = ((long)gridDim.x * blockDim.x) >> 6;
  const long tot = n * NH;
  for (long p = wid; p < tot; p += nw) {
    int hh = (int)(p % NH);
    float ai = att[hh * 128 + lane];
    float aj = att[hh * 128 + 64 + lane];
    float sv = h2[p * 64 + lane] * ai;
    float dv = fdec(hmk[p * 64 + lane]) * aj;
    sv = wave_sum64(sv);
    dv = wave_sum64(dv);
    if (lane == 0) { sal[p] = sv; dal[p] = dv; }
  }
}

// alpha (leaky-relu) + running segment max of alpha
__global__ void k_alpha(const int* __restrict__ ss, const int* __restrict__ sd,
                        const float* __restrict__ sal, const float* __restrict__ dal,
                        float* __restrict__ alpha, unsigned* __restrict__ amax, long en) {
  GS_LOOP(idx, en * NH) {
    long e = idx / NH; int hh = (int)(idx % NH);
    int s = ss[e], d = sd[e];
    float al = sal[(long)s * NH + hh] + dal[(long)d * NH + hh];
    al = (al >= 0.f) ? al : NEG_SLOPE * al;
    alpha[idx] = al;
    atomicMax(&amax[(long)d * NH + hh], fenc(al));
  }
}

// e = exp(alpha - amax[d]); alpha <- e; denom[d] += e
__global__ void k_edenom(const int* __restrict__ sd, const unsigned* __restrict__ amax,
                         float* __restrict__ alpha, float* __restrict__ denom, long en) {
  GS_LOOP(idx, en * NH) {
    long e = idx / NH; int hh = (int)(idx % NH);
    int d = sd[e];
    float am = fdec(amax[(long)d * NH + hh]);
    float ex = expf(alpha[idx] - am);
    alpha[idx] = ex;
    atomicAdd(&denom[(long)d * NH + hh], ex);
  }
}

// xm[d][c] += (1/H) * sum_h h2[s][h][c] * (e/denom)
__global__ void k_xa(const int* __restrict__ ss, const int* __restrict__ sd,
                     const float* __restrict__ h2, const float* __restrict__ ealpha,
                     const float* __restrict__ denom, float* __restrict__ xm, long en) {
  GS_LOOP(idx, en * 64) {
    long e = idx >> 6; int c = idx & 63;
    long s = ss[e], d = sd[e];
    float acc = 0.f;
    #pragma unroll
    for (int h = 0; h < NH; ++h) {
      float w = ealpha[e * NH + h] / denom[d * NH + h];
      acc = fmaf(h2[s * 384 + h * 64 + c], w, acc);
    }
    atomicAdd(&xm[d * 64 + c], acc * (1.0f / NH));
  }
}

// bsc = xm@W2 + b2 ; a <- a / max(||a||, EPS)   (one wave per node)
__global__ void k_node_fin(const float* __restrict__ xm, float* __restrict__ a,
                           const float* __restrict__ W2, const float* __restrict__ b2,
                           float* __restrict__ bsc, long n) {
  const int lane = threadIdx.x & 63;
  const long wid = ((long)blockIdx.x * blockDim.x + threadIdx.x) >> 6;
  const long nw  = ((long)gridDim.x * blockDim.x) >> 6;
  for (long i = wid; i < n; i += nw) {
    float xv = xm[i * 64 + lane];
    float av = a[i * 64 + lane];
    float dot = wave_sum64(xv * W2[lane]);
    float ss  = wave_sum64(av * av);
    float nrm = fmaxf(sqrtf(ss), COS_EPS);
    a[i * 64 + lane] = av / nrm;
    if (lane == 0) bsc[i] = dot + b2[0];
  }
}

// cossum[d] += dot(an[s], an[d])   (one wave per edge)
__global__ void k_cos(const int* __restrict__ ss, const int* __restrict__ sd,
                      const float* __restrict__ an, float* __restrict__ csum, long en) {
  const int lane = threadIdx.x & 63;
  const long wid = ((long)blockIdx.x * blockDim.x + threadIdx.x) >> 6;
  const long nw  = ((long)gridDim.x * blockDim.x) >> 6;
  for (long e = wid; e < en; e += nw) {
    long s = ss[e], d = sd[e];
    float p = wave_sum64(an[s * 64 + lane] * an[d * 64 + lane]);
    if (lane == 0) atomicAdd(&csum[d], p);
  }
}

__global__ void k_out(const float* __restrict__ bsc, const float* __restrict__ csum,
                      float* __restrict__ out, long n) {
  GS_LOOP(i, n) {
    float sc = bsc[i] * csum[i];
    out[i] = 1.0f / (1.0f + expf(-sc));
  }
}

// ---------- launcher ----------
static inline unsigned gsblocks(long total) {
  long b = (total + TPB - 1) / TPB;
  if (b > 131072) b = 131072;
  return (unsigned)b;
}

extern "C" void kernel_launch(void* const* d_in, const int* in_sizes, int n_in,
                              void* d_out, int out_size, void* d_ws, size_t ws_size,
                              hipStream_t stream) {
  const float* x   = (const float*)d_in[0];
  const float* Wg  = (const float*)d_in[1];
  const float* bg  = (const float*)d_in[2];
  const float* Wt  = (const float*)d_in[3];
  const float* att = (const float*)d_in[4];
  const float* W1  = (const float*)d_in[5];
  const float* W2  = (const float*)d_in[6];
  const float* b2  = (const float*)d_in[7];
  const int* src   = (const int*)d_in[8];
  const int* dst   = (const int*)d_in[9];
  const int* ssrc  = (const int*)d_in[10];
  const int* sdst  = (const int*)d_in[11];

  const long n   = in_sizes[0] / 64;   // 50000
  const long en  = in_sizes[8];        // E + N (src/dst, includes one loop)
  const long sen = in_sizes[10];       // N + E (sub arrays, includes one loop)

  // bump allocator over d_ws
  char* base = (char*)d_ws;
  size_t off = 0;
  auto alloc = [&](size_t bytes) -> void* {
    void* p = base + off;
    off += (bytes + 255) & ~(size_t)255;
    return p;
  };
  float*    deg   = (float*)alloc(n * 4);          // -> dinv in place
  float*    h     = (float*)alloc(n * 64 * 4);     // later: xm
  float*    xpj   = (float*)alloc(n * 64 * 4);     // later: a (normalized in place)
  float*    h2    = (float*)alloc(n * 384 * 4);
  unsigned* hmk   = (unsigned*)alloc(n * 384 * 4); // later: alpha (sen*6 floats)
  float*    sal   = (float*)alloc(n * NH * 4);
  float*    dal   = (float*)alloc(n * NH * 4);
  unsigned* amax  = (unsigned*)alloc(n * NH * 4);
  float*    denom = (float*)alloc(n * NH * 4);
  float*    bsc   = (float*)alloc(n * 4);
  float*    csum  = (float*)alloc(n * 4);
  float*    alpha = (float*)hmk;   // alias: hmk dead after k_nodedots
  float*    xm    = h;             // alias: h dead after h2 GEMM
  float*    a     = xpj;           // alias: xpj dead after h2 GEMM
  float*    out   = (float*)d_out;

  // 1) degrees -> dinv
  k_fill<<<gsblocks(n), TPB, 0, stream>>>(deg, 1.0f, n);
  k_deg<<<gsblocks(en), TPB, 0, stream>>>(dst, deg, en);
  k_dinv<<<gsblocks(n), TPB, 0, stream>>>(deg, n);

  // 2) h = x @ W_gcn
  {
    dim3 g((unsigned)((n + 3) / 4), 1);
    k_gemm64<<<g, TPB, 0, stream>>>(x, Wg, h, (int)n, 64);
  }
  // 3) xpj = b + self + aggregate
  k_xpj_init<<<gsblocks(n * 64), TPB, 0, stream>>>(h, deg, bg, xpj, n);
  k_gcn_agg<<<gsblocks(en * 64), TPB, 0, stream>>>(src, dst, h, deg, xpj, en);

  // 4) h2 = xpj @ weight   (N x 384)
  {
    dim3 g((unsigned)((n + 3) / 4), 6);
    k_gemm64<<<g, TPB, 0, stream>>>(xpj, Wt, h2, (int)n, 384);
  }

  // 5) hmax (uint keys)
  hipMemsetAsync(hmk, 0, n * 384 * 4, stream);
  k_hmax<<<gsblocks(sen * 64), TPB, 0, stream>>>(ssrc, sdst, h2, hmk, sen);

  // 6) per-node attention dots
  k_nodedots<<<gsblocks(n * NH * 64), TPB, 0, stream>>>(h2, hmk, att, sal, dal, n);

  // 7) alpha + segment max  (alpha aliases hmk — hmk dead now)
  hipMemsetAsync(amax, 0, n * NH * 4, stream);
  k_alpha<<<gsblocks(sen * NH), TPB, 0, stream>>>(ssrc, sdst, sal, dal, alpha, amax, sen);

  // 8) exp + denom
  hipMemsetAsync(denom, 0, n * NH * 4, stream);
  k_edenom<<<gsblocks(sen * NH), TPB, 0, stream>>>(sdst, amax, alpha, denom, sen);

  // 9) xa mean over heads -> xm  (xm aliases h — h dead)
  hipMemsetAsync(xm, 0, n * 64 * 4, stream);
  k_xa<<<gsblocks(sen * 64), TPB, 0, stream>>>(ssrc, sdst, h2, alpha, denom, xm, sen);

  // 10) a = xm @ W1  (a aliases xpj — xpj dead)
  {
    dim3 g((unsigned)((n + 3) / 4), 1);
    k_gemm64<<<g, TPB, 0, stream>>>(xm, W1, a, (int)n, 64);
  }
  // 11) bsc + normalize a
  k_node_fin<<<gsblocks(n * 64), TPB, 0, stream>>>(xm, a, W2, b2, bsc, n);

  // 12) cosine segment sum
  hipMemsetAsync(csum, 0, n * 4, stream);
  k_cos<<<gsblocks(sen * 64), TPB, 0, stream>>>(ssrc, sdst, a, csum, sen);

  // 13) fitness
  k_out<<<gsblocks(n), TPB, 0, stream>>>(bsc, csum, out, n);
}

// Round 3
// 1378.741 us; speedup vs baseline: 1.0436x; 1.0436x over previous
//
#include <hip/hip_runtime.h>
#include <math.h>

#define TPB 256
#define NEG_SLOPE 0.2f
#define COS_EPS 1e-8f
#define NH 6
#define GSTRIDE 68   // LDS row stride (floats): 16B-aligned rows, conflict-free

// ---------- helpers ----------
__device__ inline unsigned fenc(float f) {
  unsigned u = __float_as_uint(f);
  return u ^ ((unsigned)((int)u >> 31) | 0x80000000u);
}
__device__ inline float fdec(unsigned k) {
  unsigned u = (k & 0x80000000u) ? (k ^ 0x80000000u) : ~k;
  return __uint_as_float(u);
}
__device__ inline float wave_sum64(float v) {
  #pragma unroll
  for (int off = 32; off > 0; off >>= 1) v += __shfl_down(v, off);
  return __shfl(v, 0);
}

#define GS_LOOP(i, total) \
  for (long i = (long)blockIdx.x * blockDim.x + threadIdx.x; i < (total); \
       i += (long)gridDim.x * blockDim.x)

// ---------- tiny utility kernels ----------
__global__ void k_fill(float* p, float v, long n) { GS_LOOP(i, n) p[i] = v; }

__global__ void k_deg(const int* __restrict__ dst, float* __restrict__ deg, long en) {
  GS_LOOP(e, en) atomicAdd(&deg[dst[e]], 1.0f);
}
__global__ void k_dinv(float* __restrict__ deg, long n) {
  GS_LOOP(i, n) deg[i] = rsqrtf(fmaxf(deg[i], 1e-12f));
}

// ---------- GEMM v2: out[n][Mtot] = A[n][64] @ W[64][Mtot]
// 64x64 output tile per block, 256 threads, 4x4 register tile per thread.
// Optional fused epilogue (out2): out2 = bg[c] + out*dinv[row]^2  (GCN self-loop init)
__global__ __launch_bounds__(256)
void k_gemm64v2(const float* __restrict__ A, const float* __restrict__ W,
                float* __restrict__ out, int n, int Mtot,
                const float* __restrict__ dinv, const float* __restrict__ bg,
                float* __restrict__ out2) {
  __shared__ float At[64 * GSTRIDE];  // transposed: At[k][r]
  __shared__ float Wl[64 * GSTRIDE];  // Wl[k][c]
  const int t  = threadIdx.x;
  const int tx = t & 15;
  const int ty = t >> 4;
  const int col0 = blockIdx.y * 64;
  const long row0 = (long)blockIdx.x * 64;

  // W tile load (coalesced float4, no transpose)
  #pragma unroll
  for (int i = 0; i < 4; ++i) {
    int k = ty + 16 * i;
    float4 wv = *(const float4*)&W[(long)k * Mtot + col0 + 4 * tx];
    *(float4*)&Wl[k * GSTRIDE + 4 * tx] = wv;
  }
  // A tile load (coalesced float4) + transpose into At
  #pragma unroll
  for (int i = 0; i < 4; ++i) {
    int r = ty + 16 * i;
    long gr = row0 + r; if (gr >= n) gr = n - 1;
    float4 av = *(const float4*)&A[gr * 64 + 4 * tx];
    At[(4 * tx + 0) * GSTRIDE + r] = av.x;
    At[(4 * tx + 1) * GSTRIDE + r] = av.y;
    At[(4 * tx + 2) * GSTRIDE + r] = av.z;
    At[(4 * tx + 3) * GSTRIDE + r] = av.w;
  }
  __syncthreads();

  const int c0 = 4 * tx;
  const int r0 = 4 * ty;
  float acc[4][4] = {};
  #pragma unroll
  for (int k = 0; k < 64; ++k) {
    float4 av = *(const float4*)&At[k * GSTRIDE + r0];
    float4 wv = *(const float4*)&Wl[k * GSTRIDE + c0];
    acc[0][0] = fmaf(av.x, wv.x, acc[0][0]);
    acc[0][1] = fmaf(av.x, wv.y, acc[0][1]);
    acc[0][2] = fmaf(av.x, wv.z, acc[0][2]);
    acc[0][3] = fmaf(av.x, wv.w, acc[0][3]);
    acc[1][0] = fmaf(av.y, wv.x, acc[1][0]);
    acc[1][1] = fmaf(av.y, wv.y, acc[1][1]);
    acc[1][2] = fmaf(av.y, wv.z, acc[1][2]);
    acc[1][3] = fmaf(av.y, wv.w, acc[1][3]);
    acc[2][0] = fmaf(av.z, wv.x, acc[2][0]);
    acc[2][1] = fmaf(av.z, wv.y, acc[2][1]);
    acc[2][2] = fmaf(av.z, wv.z, acc[2][2]);
    acc[2][3] = fmaf(av.z, wv.w, acc[2][3]);
    acc[3][0] = fmaf(av.w, wv.x, acc[3][0]);
    acc[3][1] = fmaf(av.w, wv.y, acc[3][1]);
    acc[3][2] = fmaf(av.w, wv.z, acc[3][2]);
    acc[3][3] = fmaf(av.w, wv.w, acc[3][3]);
  }

  #pragma unroll
  for (int i = 0; i < 4; ++i) {
    long gr = row0 + r0 + i;
    if (gr < n) {
      float4 v = make_float4(acc[i][0], acc[i][1], acc[i][2], acc[i][3]);
      *(float4*)&out[gr * Mtot + col0 + c0] = v;
      if (out2) {
        float di = dinv[gr];
        float s = di * di;
        float4 v2 = make_float4(bg[col0 + c0 + 0] + v.x * s,
                                bg[col0 + c0 + 1] + v.y * s,
                                bg[col0 + c0 + 2] + v.z * s,
                                bg[col0 + c0 + 3] + v.w * s);
        *(float4*)&out2[gr * Mtot + col0 + c0] = v2;
      }
    }
  }
}

// GCN aggregate over the EN input pairs (includes one self-loop per node)
__global__ void k_gcn_agg(const int* __restrict__ src, const int* __restrict__ dst,
                          const float* __restrict__ h, const float* __restrict__ dinv,
                          float* __restrict__ xpj, long en) {
  GS_LOOP(idx, en * 64) {
    long e = idx >> 6; int c = idx & 63;
    int s = src[e], d = dst[e];
    float nrm = dinv[s] * dinv[d];
    atomicAdd(&xpj[(long)d * 64 + c], h[(long)s * 64 + c] * nrm);
  }
}

// per-channel segment max (uint keys); test-before-atomic to cut RMW traffic
__global__ void k_hmax(const int* __restrict__ ss, const int* __restrict__ sd,
                       const float* __restrict__ h2, unsigned* __restrict__ hmk, long en) {
  GS_LOOP(idx, en * 64) {
    long e = idx >> 6; int c = idx & 63;
    long s = ss[e], d = sd[e];
    #pragma unroll
    for (int h = 0; h < NH; ++h) {
      unsigned k = fenc(h2[s * 384 + h * 64 + c]);
      unsigned* p = &hmk[d * 384 + h * 64 + c];
      if (k > *p) atomicMax(p, k);
    }
  }
}

// per (node,head): salpha = h2[n,h,:]·att_i[h,:]; dalpha = hmax[n,h,:]·att_j[h,:]
__global__ void k_nodedots(const float* __restrict__ h2, const unsigned* __restrict__ hmk,
                           const float* __restrict__ att,
                           float* __restrict__ sal, float* __restrict__ dal, long n) {
  const int lane = threadIdx.x & 63;
  const long wid = ((long)blockIdx.x * blockDim.x + threadIdx.x) >> 6;
  const long nw  = ((long)gridDim.x * blockDim.x) >> 6;
  const long tot = n * NH;
  for (long p = wid; p < tot; p += nw) {
    int hh = (int)(p % NH);
    float ai = att[hh * 128 + lane];
    float aj = att[hh * 128 + 64 + lane];
    float sv = h2[p * 64 + lane] * ai;
    float dv = fdec(hmk[p * 64 + lane]) * aj;
    sv = wave_sum64(sv);
    dv = wave_sum64(dv);
    if (lane == 0) { sal[p] = sv; dal[p] = dv; }
  }
}

// alpha (leaky-relu) + running segment max of alpha (test-before-atomic)
__global__ void k_alpha(const int* __restrict__ ss, const int* __restrict__ sd,
                        const float* __restrict__ sal, const float* __restrict__ dal,
                        float* __restrict__ alpha, unsigned* __restrict__ amax, long en) {
  GS_LOOP(idx, en * NH) {
    long e = idx / NH; int hh = (int)(idx % NH);
    int s = ss[e], d = sd[e];
    float al = sal[(long)s * NH + hh] + dal[(long)d * NH + hh];
    al = (al >= 0.f) ? al : NEG_SLOPE * al;
    alpha[idx] = al;
    unsigned k = fenc(al);
    unsigned* p = &amax[(long)d * NH + hh];
    if (k > *p) atomicMax(p, k);
  }
}

// e = exp(alpha - amax[d]); alpha <- e; denom[d] += e
__global__ void k_edenom(const int* __restrict__ sd, const unsigned* __restrict__ amax,
                         float* __restrict__ alpha, float* __restrict__ denom, long en) {
  GS_LOOP(idx, en * NH) {
    long e = idx / NH; int hh = (int)(idx % NH);
    int d = sd[e];
    float am = fdec(amax[(long)d * NH + hh]);
    float ex = expf(alpha[idx] - am);
    alpha[idx] = ex;
    atomicAdd(&denom[(long)d * NH + hh], ex);
  }
}

// normalize weights once per (edge, head): alpha <- alpha / denom[d]
__global__ void k_normw(const int* __restrict__ sd, const float* __restrict__ denom,
                        float* __restrict__ alpha, long en) {
  GS_LOOP(idx, en * NH) {
    long e = idx / NH; int hh = (int)(idx % NH);
    int d = sd[e];
    alpha[idx] /= denom[(long)d * NH + hh];
  }
}

// xm[d][c] += (1/H) * sum_h h2[s][h][c] * w[e][h]
__global__ void k_xa(const int* __restrict__ ss, const int* __restrict__ sd,
                     const float* __restrict__ h2, const float* __restrict__ w,
                     float* __restrict__ xm, long en) {
  GS_LOOP(idx, en * 64) {
    long e = idx >> 6; int c = idx & 63;
    long s = ss[e], d = sd[e];
    float acc = 0.f;
    #pragma unroll
    for (int h = 0; h < NH; ++h)
      acc = fmaf(h2[s * 384 + h * 64 + c], w[e * NH + h], acc);
    atomicAdd(&xm[d * 64 + c], acc * (1.0f / NH));
  }
}

// bsc = xm@W2 + b2 ; a <- a / max(||a||, EPS)   (one wave per node)
__global__ void k_node_fin(const float* __restrict__ xm, float* __restrict__ a,
                           const float* __restrict__ W2, const float* __restrict__ b2,
                           float* __restrict__ bsc, long n) {
  const int lane = threadIdx.x & 63;
  const long wid = ((long)blockIdx.x * blockDim.x + threadIdx.x) >> 6;
  const long nw  = ((long)gridDim.x * blockDim.x) >> 6;
  for (long i = wid; i < n; i += nw) {
    float xv = xm[i * 64 + lane];
    float av = a[i * 64 + lane];
    float dot = wave_sum64(xv * W2[lane]);
    float ss  = wave_sum64(av * av);
    float nrm = fmaxf(sqrtf(ss), COS_EPS);
    a[i * 64 + lane] = av / nrm;
    if (lane == 0) bsc[i] = dot + b2[0];
  }
}

// cossum[d] += dot(an[s], an[d])   (one wave per edge)
__global__ void k_cos(const int* __restrict__ ss, const int* __restrict__ sd,
                      const float* __restrict__ an, float* __restrict__ csum, long en) {
  const int lane = threadIdx.x & 63;
  const long wid = ((long)blockIdx.x * blockDim.x + threadIdx.x) >> 6;
  const long nw  = ((long)gridDim.x * blockDim.x) >> 6;
  for (long e = wid; e < en; e += nw) {
    long s = ss[e], d = sd[e];
    float p = wave_sum64(an[s * 64 + lane] * an[d * 64 + lane]);
    if (lane == 0) atomicAdd(&csum[d], p);
  }
}

__global__ void k_out(const float* __restrict__ bsc, const float* __restrict__ csum,
                      float* __restrict__ out, long n) {
  GS_LOOP(i, n) {
    float sc = bsc[i] * csum[i];
    out[i] = 1.0f / (1.0f + expf(-sc));
  }
}

// ---------- launcher ----------
static inline unsigned gsblocks(long total) {
  long b = (total + TPB - 1) / TPB;
  if (b > 131072) b = 131072;
  return (unsigned)b;
}

extern "C" void kernel_launch(void* const* d_in, const int* in_sizes, int n_in,
                              void* d_out, int out_size, void* d_ws, size_t ws_size,
                              hipStream_t stream) {
  const float* x   = (const float*)d_in[0];
  const float* Wg  = (const float*)d_in[1];
  const float* bg  = (const float*)d_in[2];
  const float* Wt  = (const float*)d_in[3];
  const float* att = (const float*)d_in[4];
  const float* W1  = (const float*)d_in[5];
  const float* W2  = (const float*)d_in[6];
  const float* b2  = (const float*)d_in[7];
  const int* src   = (const int*)d_in[8];
  const int* dst   = (const int*)d_in[9];
  const int* ssrc  = (const int*)d_in[10];
  const int* sdst  = (const int*)d_in[11];

  const long n   = in_sizes[0] / 64;   // 50000
  const long en  = in_sizes[8];        // E + N
  const long sen = in_sizes[10];       // N + E

  char* base = (char*)d_ws;
  size_t off = 0;
  auto alloc = [&](size_t bytes) -> void* {
    void* p = base + off;
    off += (bytes + 255) & ~(size_t)255;
    return p;
  };
  float*    deg   = (float*)alloc(n * 4);          // -> dinv in place
  float*    h     = (float*)alloc(n * 64 * 4);     // later: xm
  float*    xpj   = (float*)alloc(n * 64 * 4);     // later: a
  float*    h2    = (float*)alloc(n * 384 * 4);
  unsigned* hmk   = (unsigned*)alloc(n * 384 * 4); // later: alpha (sen*6 floats)
  float*    sal   = (float*)alloc(n * NH * 4);
  float*    dal   = (float*)alloc(n * NH * 4);
  unsigned* amax  = (unsigned*)alloc(n * NH * 4);
  float*    denom = (float*)alloc(n * NH * 4);
  float*    bsc   = (float*)alloc(n * 4);
  float*    csum  = (float*)alloc(n * 4);
  float*    alpha = (float*)hmk;   // alias: hmk dead after k_nodedots
  float*    xm    = h;             // alias: h dead after h2 GEMM
  float*    a     = xpj;           // alias: xpj dead after h2 GEMM
  float*    out   = (float*)d_out;

  const unsigned rowblk = (unsigned)((n + 63) / 64);

  // 1) degrees -> dinv
  k_fill<<<gsblocks(n), TPB, 0, stream>>>(deg, 1.0f, n);
  k_deg<<<gsblocks(en), TPB, 0, stream>>>(dst, deg, en);
  k_dinv<<<gsblocks(n), TPB, 0, stream>>>(deg, n);

  // 2) h = x @ W_gcn, fused xpj = bg + h*dinv^2 (self-loop term)
  {
    dim3 g(rowblk, 1);
    k_gemm64v2<<<g, 256, 0, stream>>>(x, Wg, h, (int)n, 64, deg, bg, xpj);
  }
  // 3) aggregate neighbors into xpj
  k_gcn_agg<<<gsblocks(en * 64), TPB, 0, stream>>>(src, dst, h, deg, xpj, en);

  // 4) h2 = xpj @ weight   (N x 384)
  {
    dim3 g(rowblk, 6);
    k_gemm64v2<<<g, 256, 0, stream>>>(xpj, Wt, h2, (int)n, 384, nullptr, nullptr, nullptr);
  }

  // 5) hmax (uint keys)
  hipMemsetAsync(hmk, 0, n * 384 * 4, stream);
  k_hmax<<<gsblocks(sen * 64), TPB, 0, stream>>>(ssrc, sdst, h2, hmk, sen);

  // 6) per-node attention dots
  k_nodedots<<<gsblocks(n * NH * 64), TPB, 0, stream>>>(h2, hmk, att, sal, dal, n);

  // 7) alpha + segment max (alpha aliases hmk)
  hipMemsetAsync(amax, 0, n * NH * 4, stream);
  k_alpha<<<gsblocks(sen * NH), TPB, 0, stream>>>(ssrc, sdst, sal, dal, alpha, amax, sen);

  // 8) exp + denom
  hipMemsetAsync(denom, 0, n * NH * 4, stream);
  k_edenom<<<gsblocks(sen * NH), TPB, 0, stream>>>(sdst, amax, alpha, denom, sen);

  // 8b) normalize weights once per (edge, head)
  k_normw<<<gsblocks(sen * NH), TPB, 0, stream>>>(sdst, denom, alpha, sen);

  // 9) xa mean over heads -> xm (aliases h)
  hipMemsetAsync(xm, 0, n * 64 * 4, stream);
  k_xa<<<gsblocks(sen * 64), TPB, 0, stream>>>(ssrc, sdst, h2, alpha, xm, sen);

  // 10) a = xm @ W1 (aliases xpj)
  {
    dim3 g(rowblk, 1);
    k_gemm64v2<<<g, 256, 0, stream>>>(xm, W1, a, (int)n, 64, nullptr, nullptr, nullptr);
  }
  // 11) bsc + normalize a
  k_node_fin<<<gsblocks(n * 64), TPB, 0, stream>>>(xm, a, W2, b2, bsc, n);

  // 12) cosine segment sum
  hipMemsetAsync(csum, 0, n * 4, stream);
  k_cos<<<gsblocks(sen * 64), TPB, 0, stream>>>(ssrc, sdst, a, csum, sen);

  // 13) fitness
  k_out<<<gsblocks(n), TPB, 0, stream>>>(bsc, csum, out, n);
}

// Round 4
// 683.036 us; speedup vs baseline: 2.1066x; 2.0185x over previous
//
#include <hip/hip_runtime.h>
#include <math.h>

#define TPB 256
#define NEG_SLOPE 0.2f
#define COS_EPS 1e-8f
#define NH 6
#define GSTRIDE 68   // LDS row stride (floats) for GEMM tiles

// ---------- helpers ----------
__device__ inline float wave_sum64(float v) {
  #pragma unroll
  for (int off = 32; off > 0; off >>= 1) v += __shfl_down(v, off);
  return __shfl(v, 0);
}
__device__ inline float wave_max64(float v) {
  #pragma unroll
  for (int off = 32; off > 0; off >>= 1) v = fmaxf(v, __shfl_down(v, off));
  return __shfl(v, 0);
}

#define GS_LOOP(i, total) \
  for (long i = (long)blockIdx.x * blockDim.x + threadIdx.x; i < (total); \
       i += (long)gridDim.x * blockDim.x)

// ---------- CSR build ----------
__global__ void k_cnt(const int* __restrict__ dst, const int* __restrict__ sdst,
                      int* __restrict__ gcnt, int* __restrict__ scnt,
                      long en, long sen) {
  long mx = en > sen ? en : sen;
  GS_LOOP(e, mx) {
    if (e < en)  atomicAdd(&gcnt[dst[e]], 1);
    if (e < sen) atomicAdd(&scnt[sdst[e]], 1);
  }
}

// dinv = rsqrt(gcnt + 1)   (gcnt counts en entries incl. one loop; _gcn adds another)
__global__ void k_dinv(const int* __restrict__ gcnt, float* __restrict__ dinv, long n) {
  GS_LOOP(i, n) dinv[i] = rsqrtf(fmaxf((float)gcnt[i] + 1.0f, 1e-12f));
}

// single-block hierarchical exclusive scan: off[n+1], cur[i]=off[i]
__global__ __launch_bounds__(1024)
void k_scan(const int* __restrict__ cnt, int* __restrict__ off,
            int* __restrict__ cur, int n) {
  __shared__ int wsum[16];
  __shared__ int carry_s;
  const int t = threadIdx.x; const int lane = t & 63; const int wv = t >> 6;
  if (t == 0) { carry_s = 0; off[0] = 0; }
  __syncthreads();
  for (int base = 0; base < n; base += 1024) {
    int idx = base + t;
    int v = (idx < n) ? cnt[idx] : 0;
    int x = v;
    #pragma unroll
    for (int s = 1; s < 64; s <<= 1) {
      int y = __shfl_up(x, s);
      if (lane >= s) x += y;
    }
    if (lane == 63) wsum[wv] = x;
    __syncthreads();
    if (wv == 0 && lane < 16) {
      int w = wsum[lane];
      #pragma unroll
      for (int s = 1; s < 16; s <<= 1) {
        int y = __shfl_up(w, s);
        if (lane >= s) w += y;
      }
      wsum[lane] = w;
    }
    __syncthreads();
    int waveoff = (wv == 0) ? 0 : wsum[wv - 1];
    int carry = carry_s;
    int inc = carry + waveoff + x;
    if (idx < n) { off[idx + 1] = inc; cur[idx] = inc - v; }
    __syncthreads();
    if (t == 1023) carry_s = carry + wsum[15];
    __syncthreads();
  }
}

__global__ void k_scatter(const int* __restrict__ src, const int* __restrict__ dst,
                          const int* __restrict__ ssrc, const int* __restrict__ sdst,
                          int* __restrict__ gcur, int* __restrict__ gcsr,
                          int* __restrict__ scur, int* __restrict__ scsr,
                          long en, long sen) {
  long mx = en > sen ? en : sen;
  GS_LOOP(e, mx) {
    if (e < en)  { int d = dst[e];  int p = atomicAdd(&gcur[d], 1); gcsr[p] = src[e]; }
    if (e < sen) { int d = sdst[e]; int p = atomicAdd(&scur[d], 1); scsr[p] = ssrc[e]; }
  }
}

// ---------- GEMM: out[n][Mtot] = A[n][64] @ W[64][Mtot], 64x64 tile, 4x4 reg tile
__global__ __launch_bounds__(256)
void k_gemm64v2(const float* __restrict__ A, const float* __restrict__ W,
                float* __restrict__ out, int n, int Mtot) {
  __shared__ float At[64 * GSTRIDE];
  __shared__ float Wl[64 * GSTRIDE];
  const int t  = threadIdx.x;
  const int tx = t & 15;
  const int ty = t >> 4;
  const int col0 = blockIdx.y * 64;
  const long row0 = (long)blockIdx.x * 64;

  #pragma unroll
  for (int i = 0; i < 4; ++i) {
    int k = ty + 16 * i;
    float4 wv = *(const float4*)&W[(long)k * Mtot + col0 + 4 * tx];
    *(float4*)&Wl[k * GSTRIDE + 4 * tx] = wv;
  }
  #pragma unroll
  for (int i = 0; i < 4; ++i) {
    int r = ty + 16 * i;
    long gr = row0 + r; if (gr >= n) gr = n - 1;
    float4 av = *(const float4*)&A[gr * 64 + 4 * tx];
    At[(4 * tx + 0) * GSTRIDE + r] = av.x;
    At[(4 * tx + 1) * GSTRIDE + r] = av.y;
    At[(4 * tx + 2) * GSTRIDE + r] = av.z;
    At[(4 * tx + 3) * GSTRIDE + r] = av.w;
  }
  __syncthreads();

  const int c0 = 4 * tx;
  const int r0 = 4 * ty;
  float acc[4][4] = {};
  #pragma unroll
  for (int k = 0; k < 64; ++k) {
    float4 av = *(const float4*)&At[k * GSTRIDE + r0];
    float4 wv = *(const float4*)&Wl[k * GSTRIDE + c0];
    acc[0][0] = fmaf(av.x, wv.x, acc[0][0]); acc[0][1] = fmaf(av.x, wv.y, acc[0][1]);
    acc[0][2] = fmaf(av.x, wv.z, acc[0][2]); acc[0][3] = fmaf(av.x, wv.w, acc[0][3]);
    acc[1][0] = fmaf(av.y, wv.x, acc[1][0]); acc[1][1] = fmaf(av.y, wv.y, acc[1][1]);
    acc[1][2] = fmaf(av.y, wv.z, acc[1][2]); acc[1][3] = fmaf(av.y, wv.w, acc[1][3]);
    acc[2][0] = fmaf(av.z, wv.x, acc[2][0]); acc[2][1] = fmaf(av.z, wv.y, acc[2][1]);
    acc[2][2] = fmaf(av.z, wv.z, acc[2][2]); acc[2][3] = fmaf(av.z, wv.w, acc[2][3]);
    acc[3][0] = fmaf(av.w, wv.x, acc[3][0]); acc[3][1] = fmaf(av.w, wv.y, acc[3][1]);
    acc[3][2] = fmaf(av.w, wv.z, acc[3][2]); acc[3][3] = fmaf(av.w, wv.w, acc[3][3]);
  }
  #pragma unroll
  for (int i = 0; i < 4; ++i) {
    long gr = row0 + r0 + i;
    if (gr < n)
      *(float4*)&out[gr * Mtot + col0 + c0] =
        make_float4(acc[i][0], acc[i][1], acc[i][2], acc[i][3]);
  }
}

// ---------- GCN aggregate via CSR (wave per node, lane = channel) ----------
__global__ __launch_bounds__(256)
void k_gcn_csr(const int* __restrict__ goff, const int* __restrict__ gcsr,
               const float* __restrict__ h, const float* __restrict__ dinv,
               const float* __restrict__ bg, float* __restrict__ xpj, int n) {
  const int lane = threadIdx.x & 63;
  const int d = blockIdx.x * 4 + (threadIdx.x >> 6);
  if (d >= n) return;
  const int o0 = goff[d], o1 = goff[d + 1];
  float acc = 0.f;
  for (int j = o0; j < o1; ++j) {
    int s = gcsr[j];
    acc = fmaf(h[(long)s * 64 + lane], dinv[s], acc);
  }
  float di = dinv[d];
  xpj[(long)d * 64 + lane] = bg[lane] + di * acc + h[(long)d * 64 + lane] * di * di;
}

// ---------- per-node source-attention dots: sal[n][h] = h2[n,h,:]·att_i[h,:]
__global__ __launch_bounds__(256)
void k_sal(const float* __restrict__ h2, const float* __restrict__ att,
           float* __restrict__ sal, int n) {
  const int lane = threadIdx.x & 63;
  const int d = blockIdx.x * 4 + (threadIdx.x >> 6);
  if (d >= n) return;
  #pragma unroll
  for (int h = 0; h < NH; ++h) {
    float sv = wave_sum64(h2[(long)d * 384 + h * 64 + lane] * att[h * 128 + lane]);
    if (lane == 0) sal[(long)d * NH + h] = sv;
  }
}

// ---------- fused attention mega-kernel (wave per node) ----------
// hmax -> dal -> alpha -> softmax -> weighted aggregate -> xm. No atomics.
__global__ __launch_bounds__(256)
void k_mega(const int* __restrict__ soff, const int* __restrict__ scsr,
            const float* __restrict__ h2, const float* __restrict__ sal,
            const float* __restrict__ att, float* __restrict__ xm, int n) {
  const int lane = threadIdx.x & 63;
  const int d = blockIdx.x * 4 + (threadIdx.x >> 6);
  if (d >= n) return;
  const int o0 = soff[d], o1 = soff[d + 1];

  float attj[NH];
  #pragma unroll
  for (int h = 0; h < NH; ++h) attj[h] = att[h * 128 + 64 + lane];

  // Pass 1: per-channel max over neighbor h2 rows (hmax kept in registers)
  float hm[NH];
  #pragma unroll
  for (int h = 0; h < NH; ++h) hm[h] = -INFINITY;
  for (int j = o0; j < o1; ++j) {
    long s = scsr[j];
    #pragma unroll
    for (int h = 0; h < NH; ++h)
      hm[h] = fmaxf(hm[h], h2[s * 384 + h * 64 + lane]);
  }
  float dal[NH];
  #pragma unroll
  for (int h = 0; h < NH; ++h) dal[h] = wave_sum64(hm[h] * attj[h]);

  // Pass 2: per-head max of alpha over this node's edges (lane = edge)
  float mx[NH];
  #pragma unroll
  for (int h = 0; h < NH; ++h) mx[h] = -INFINITY;
  for (int base = o0; base < o1; base += 64) {
    int j = base + lane;
    float a6[NH];
    if (j < o1) {
      long s = scsr[j];
      #pragma unroll
      for (int h = 0; h < NH; ++h) {
        float al = sal[s * NH + h] + dal[h];
        a6[h] = (al >= 0.f) ? al : NEG_SLOPE * al;
      }
    } else {
      #pragma unroll
      for (int h = 0; h < NH; ++h) a6[h] = -INFINITY;
    }
    #pragma unroll
    for (int h = 0; h < NH; ++h) mx[h] = fmaxf(mx[h], wave_max64(a6[h]));
  }

  // Pass 3: exp / denom, then accumulate per-head aggregates (lane = channel)
  float den[NH], acc[NH];
  #pragma unroll
  for (int h = 0; h < NH; ++h) { den[h] = 0.f; acc[h] = 0.f; }
  for (int base = o0; base < o1; base += 64) {
    int cs = o1 - base; if (cs > 64) cs = 64;
    int j = base + lane;
    float e6[NH];
    int s = 0;
    if (j < o1) {
      s = scsr[j];
      #pragma unroll
      for (int h = 0; h < NH; ++h) {
        float al = sal[(long)s * NH + h] + dal[h];
        al = (al >= 0.f) ? al : NEG_SLOPE * al;
        e6[h] = expf(al - mx[h]);
      }
    } else {
      #pragma unroll
      for (int h = 0; h < NH; ++h) e6[h] = 0.f;
    }
    #pragma unroll
    for (int h = 0; h < NH; ++h) den[h] += wave_sum64(e6[h]);
    // broadcast each edge's (s, weights) and accumulate its h2 row
    for (int jj = 0; jj < cs; ++jj) {
      long sj = __shfl(s, jj);
      #pragma unroll
      for (int h = 0; h < NH; ++h) {
        float w = __shfl(e6[h], jj);
        acc[h] = fmaf(h2[sj * 384 + h * 64 + lane], w, acc[h]);
      }
    }
  }
  float o = 0.f;
  #pragma unroll
  for (int h = 0; h < NH; ++h) o += acc[h] / den[h];
  xm[(long)d * 64 + lane] = o * (1.0f / NH);
}

// bsc = xm@W2 + b2 ; a <- a / max(||a||, EPS)   (wave per node)
__global__ __launch_bounds__(256)
void k_node_fin(const float* __restrict__ xm, float* __restrict__ a,
                const float* __restrict__ W2, const float* __restrict__ b2,
                float* __restrict__ bsc, int n) {
  const int lane = threadIdx.x & 63;
  const int i = blockIdx.x * 4 + (threadIdx.x >> 6);
  if (i >= n) return;
  float xv = xm[(long)i * 64 + lane];
  float av = a[(long)i * 64 + lane];
  float dot = wave_sum64(xv * W2[lane]);
  float ss  = wave_sum64(av * av);
  float nrm = fmaxf(sqrtf(ss), COS_EPS);
  a[(long)i * 64 + lane] = av / nrm;
  if (lane == 0) bsc[i] = dot + b2[0];
}

// fitness[d] = sigmoid(bsc[d] * sum_j dot(an[s_j], an[d]))   (wave per node)
__global__ __launch_bounds__(256)
void k_cosout(const int* __restrict__ soff, const int* __restrict__ scsr,
              const float* __restrict__ an, const float* __restrict__ bsc,
              float* __restrict__ out, int n) {
  const int lane = threadIdx.x & 63;
  const int d = blockIdx.x * 4 + (threadIdx.x >> 6);
  if (d >= n) return;
  const int o0 = soff[d], o1 = soff[d + 1];
  float ad = an[(long)d * 64 + lane];
  float cs = 0.f;
  for (int j = o0; j < o1; ++j) {
    long s = scsr[j];
    cs += wave_sum64(ad * an[s * 64 + lane]);
  }
  if (lane == 0) {
    float sc = bsc[d] * cs;
    out[d] = 1.0f / (1.0f + expf(-sc));
  }
}

// ---------- launcher ----------
static inline unsigned gsblocks(long total) {
  long b = (total + TPB - 1) / TPB;
  if (b > 131072) b = 131072;
  return (unsigned)b;
}

extern "C" void kernel_launch(void* const* d_in, const int* in_sizes, int n_in,
                              void* d_out, int out_size, void* d_ws, size_t ws_size,
                              hipStream_t stream) {
  const float* x   = (const float*)d_in[0];
  const float* Wg  = (const float*)d_in[1];
  const float* bg  = (const float*)d_in[2];
  const float* Wt  = (const float*)d_in[3];
  const float* att = (const float*)d_in[4];
  const float* W1  = (const float*)d_in[5];
  const float* W2  = (const float*)d_in[6];
  const float* b2  = (const float*)d_in[7];
  const int* src   = (const int*)d_in[8];
  const int* dst   = (const int*)d_in[9];
  const int* ssrc  = (const int*)d_in[10];
  const int* sdst  = (const int*)d_in[11];

  const long n   = in_sizes[0] / 64;   // 50000
  const long en  = in_sizes[8];        // E + N
  const long sen = in_sizes[10];       // N + E

  char* base = (char*)d_ws;
  size_t off = 0;
  auto alloc = [&](size_t bytes) -> void* {
    void* p = base + off;
    off += (bytes + 255) & ~(size_t)255;
    return p;
  };
  int*   gcnt = (int*)alloc(n * 4);
  int*   scnt = (int*)alloc(n * 4);
  int*   goff = (int*)alloc((n + 1) * 4);
  int*   soff = (int*)alloc((n + 1) * 4);
  int*   gcur = (int*)alloc(n * 4);
  int*   scur = (int*)alloc(n * 4);
  int*   gcsr = (int*)alloc(en * 4);
  int*   scsr = (int*)alloc(sen * 4);
  float* dinv = (float*)alloc(n * 4);
  float* h    = (float*)alloc(n * 64 * 4);   // later: xm
  float* xpj  = (float*)alloc(n * 64 * 4);   // later: a
  float* h2   = (float*)alloc(n * 384 * 4);
  float* sal  = (float*)alloc(n * NH * 4);
  float* bsc  = (float*)alloc(n * 4);
  float* xm   = h;     // alias: h dead after k_gcn_csr
  float* a    = xpj;   // alias: xpj dead after h2 GEMM
  float* out  = (float*)d_out;

  const unsigned rowblk  = (unsigned)((n + 63) / 64);
  const unsigned nodeblk = (unsigned)((n + 3) / 4);

  // ---- CSR build (both graphs) ----
  hipMemsetAsync(gcnt, 0, n * 4, stream);
  hipMemsetAsync(scnt, 0, n * 4, stream);
  k_cnt<<<gsblocks(en), TPB, 0, stream>>>(dst, sdst, gcnt, scnt, en, sen);
  k_dinv<<<gsblocks(n), TPB, 0, stream>>>(gcnt, dinv, n);
  k_scan<<<1, 1024, 0, stream>>>(gcnt, goff, gcur, (int)n);
  k_scan<<<1, 1024, 0, stream>>>(scnt, soff, scur, (int)n);
  k_scatter<<<gsblocks(en), TPB, 0, stream>>>(src, dst, ssrc, sdst,
                                              gcur, gcsr, scur, scsr, en, sen);

  // ---- h = x @ W_gcn ----
  { dim3 g(rowblk, 1); k_gemm64v2<<<g, 256, 0, stream>>>(x, Wg, h, (int)n, 64); }

  // ---- xpj = GCN(h) via CSR ----
  k_gcn_csr<<<nodeblk, 256, 0, stream>>>(goff, gcsr, h, dinv, bg, xpj, (int)n);

  // ---- h2 = xpj @ weight ----
  { dim3 g(rowblk, 6); k_gemm64v2<<<g, 256, 0, stream>>>(xpj, Wt, h2, (int)n, 384); }

  // ---- sal ----
  k_sal<<<nodeblk, 256, 0, stream>>>(h2, att, sal, (int)n);

  // ---- fused attention (hmax+alpha+softmax+aggregate) -> xm ----
  k_mega<<<nodeblk, 256, 0, stream>>>(soff, scsr, h2, sal, att, xm, (int)n);

  // ---- a = xm @ W1 ----
  { dim3 g(rowblk, 1); k_gemm64v2<<<g, 256, 0, stream>>>(xm, W1, a, (int)n, 64); }

  // ---- bsc + normalize a ----
  k_node_fin<<<nodeblk, 256, 0, stream>>>(xm, a, W2, b2, bsc, (int)n);

  // ---- cosine + sigmoid -> out ----
  k_cosout<<<nodeblk, 256, 0, stream>>>(soff, scsr, a, bsc, out, (int)n);
}

// Round 5
// 514.749 us; speedup vs baseline: 2.7953x; 1.3269x over previous
//
#include <hip/hip_runtime.h>
#include <math.h>

#define TPB 256
#define NEG_SLOPE 0.2f
#define COS_EPS 1e-8f
#define NH 6
#define GSTRIDE 68   // LDS row stride (floats) for GEMM tiles

// ---------- helpers ----------
__device__ inline float wave_sum64(float v) {
  #pragma unroll
  for (int off = 32; off > 0; off >>= 1) v += __shfl_down(v, off);
  return __shfl(v, 0);
}
__device__ inline float wave_max64(float v) {
  #pragma unroll
  for (int off = 32; off > 0; off >>= 1) v = fmaxf(v, __shfl_down(v, off));
  return __shfl(v, 0);
}
__device__ inline unsigned short f2bf(float f) {
  unsigned u = __float_as_uint(f);
  unsigned r = (u + 0x7fffu + ((u >> 16) & 1u)) >> 16;   // round-to-nearest-even
  return (unsigned short)r;
}
__device__ inline float bf2f(unsigned short b) {
  return __uint_as_float(((unsigned)b) << 16);
}

#define GS_LOOP(i, total) \
  for (long i = (long)blockIdx.x * blockDim.x + threadIdx.x; i < (total); \
       i += (long)gridDim.x * blockDim.x)

// ---------- CSR build ----------
__global__ void k_cnt(const int* __restrict__ dst, const int* __restrict__ sdst,
                      int* __restrict__ gcnt, int* __restrict__ scnt,
                      long en, long sen) {
  long mx = en > sen ? en : sen;
  GS_LOOP(e, mx) {
    if (e < en)  atomicAdd(&gcnt[dst[e]], 1);
    if (e < sen) atomicAdd(&scnt[sdst[e]], 1);
  }
}

__global__ void k_dinv(const int* __restrict__ gcnt, float* __restrict__ dinv, long n) {
  GS_LOOP(i, n) dinv[i] = rsqrtf(fmaxf((float)gcnt[i] + 1.0f, 1e-12f));
}

// fast single-block scan: chunk sums -> block scan -> chunk writeback.
// blockIdx.x selects which (cnt,off,cur) triple to scan.
__global__ __launch_bounds__(1024)
void k_scan2(const int* __restrict__ gcnt, int* __restrict__ goff, int* __restrict__ gcur,
             const int* __restrict__ scnt, int* __restrict__ soff, int* __restrict__ scur,
             int n) {
  const int* cnt = blockIdx.x ? scnt : gcnt;
  int* off = blockIdx.x ? soff : goff;
  int* cur = blockIdx.x ? scur : gcur;

  const int t = threadIdx.x;
  const int chunk = (n + 1023) >> 10;
  int lo = t * chunk; if (lo > n) lo = n;
  int hi = lo + chunk; if (hi > n) hi = n;

  int s = 0;
  for (int i = lo; i < hi; ++i) s += cnt[i];

  __shared__ int wsum[16];
  const int lane = t & 63, wv = t >> 6;
  int x = s;
  #pragma unroll
  for (int d = 1; d < 64; d <<= 1) {
    int y = __shfl_up(x, d);
    if (lane >= d) x += y;
  }
  if (lane == 63) wsum[wv] = x;
  __syncthreads();
  if (t < 16) {
    int w = wsum[t];
    #pragma unroll
    for (int d = 1; d < 16; d <<= 1) {
      int y = __shfl_up(w, d);
      if (t >= d) w += y;
    }
    wsum[t] = w;
  }
  __syncthreads();
  int run = x - s + (wv ? wsum[wv - 1] : 0);   // exclusive prefix for this thread
  if (t == 0) off[0] = 0;
  for (int i = lo; i < hi; ++i) {
    int v = cnt[i];
    cur[i] = run;
    run += v;
    off[i + 1] = run;
  }
}

__global__ void k_scatter(const int* __restrict__ src, const int* __restrict__ dst,
                          const int* __restrict__ ssrc, const int* __restrict__ sdst,
                          int* __restrict__ gcur, int* __restrict__ gcsr,
                          int* __restrict__ scur, int* __restrict__ scsr,
                          long en, long sen) {
  long mx = en > sen ? en : sen;
  GS_LOOP(e, mx) {
    if (e < en)  { int d = dst[e];  int p = atomicAdd(&gcur[d], 1); gcsr[p] = src[e]; }
    if (e < sen) { int d = sdst[e]; int p = atomicAdd(&scur[d], 1); scsr[p] = ssrc[e]; }
  }
}

// ---------- GEMM: A[n][64] @ W[64][Mtot], 64x64 tile, 4x4 reg tile.
// out32 != null -> fp32 output. out16 != null -> bf16 output, and if sal != null
// also emits sal[row][h] = fp32 dot(out_row_tile, att[h,0:64]) with h = blockIdx.y.
__global__ __launch_bounds__(256)
void k_gemm64v2(const float* __restrict__ A, const float* __restrict__ W,
                float* __restrict__ out32, unsigned short* __restrict__ out16,
                const float* __restrict__ att, float* __restrict__ sal,
                int n, int Mtot) {
  __shared__ float At[64 * GSTRIDE];
  __shared__ float Wl[64 * GSTRIDE];
  const int t  = threadIdx.x;
  const int tx = t & 15;
  const int ty = t >> 4;
  const int col0 = blockIdx.y * 64;
  const long row0 = (long)blockIdx.x * 64;

  #pragma unroll
  for (int i = 0; i < 4; ++i) {
    int k = ty + 16 * i;
    float4 wv = *(const float4*)&W[(long)k * Mtot + col0 + 4 * tx];
    *(float4*)&Wl[k * GSTRIDE + 4 * tx] = wv;
  }
  #pragma unroll
  for (int i = 0; i < 4; ++i) {
    int r = ty + 16 * i;
    long gr = row0 + r; if (gr >= n) gr = n - 1;
    float4 av = *(const float4*)&A[gr * 64 + 4 * tx];
    At[(4 * tx + 0) * GSTRIDE + r] = av.x;
    At[(4 * tx + 1) * GSTRIDE + r] = av.y;
    At[(4 * tx + 2) * GSTRIDE + r] = av.z;
    At[(4 * tx + 3) * GSTRIDE + r] = av.w;
  }
  __syncthreads();

  const int c0 = 4 * tx;
  const int r0 = 4 * ty;
  float acc[4][4] = {};
  #pragma unroll
  for (int k = 0; k < 64; ++k) {
    float4 av = *(const float4*)&At[k * GSTRIDE + r0];
    float4 wv = *(const float4*)&Wl[k * GSTRIDE + c0];
    acc[0][0] = fmaf(av.x, wv.x, acc[0][0]); acc[0][1] = fmaf(av.x, wv.y, acc[0][1]);
    acc[0][2] = fmaf(av.x, wv.z, acc[0][2]); acc[0][3] = fmaf(av.x, wv.w, acc[0][3]);
    acc[1][0] = fmaf(av.y, wv.x, acc[1][0]); acc[1][1] = fmaf(av.y, wv.y, acc[1][1]);
    acc[1][2] = fmaf(av.y, wv.z, acc[1][2]); acc[1][3] = fmaf(av.y, wv.w, acc[1][3]);
    acc[2][0] = fmaf(av.z, wv.x, acc[2][0]); acc[2][1] = fmaf(av.z, wv.y, acc[2][1]);
    acc[2][2] = fmaf(av.z, wv.z, acc[2][2]); acc[2][3] = fmaf(av.z, wv.w, acc[2][3]);
    acc[3][0] = fmaf(av.w, wv.x, acc[3][0]); acc[3][1] = fmaf(av.w, wv.y, acc[3][1]);
    acc[3][2] = fmaf(av.w, wv.z, acc[3][2]); acc[3][3] = fmaf(av.w, wv.w, acc[3][3]);
  }

  if (out32) {
    #pragma unroll
    for (int i = 0; i < 4; ++i) {
      long gr = row0 + r0 + i;
      if (gr < n)
        *(float4*)&out32[gr * Mtot + col0 + c0] =
          make_float4(acc[i][0], acc[i][1], acc[i][2], acc[i][3]);
    }
  }
  if (out16) {
    #pragma unroll
    for (int i = 0; i < 4; ++i) {
      long gr = row0 + r0 + i;
      if (gr < n) {
        ushort4 v;
        v.x = f2bf(acc[i][0]); v.y = f2bf(acc[i][1]);
        v.z = f2bf(acc[i][2]); v.w = f2bf(acc[i][3]);
        *(ushort4*)&out16[gr * Mtot + col0 + c0] = v;
      }
    }
    if (sal) {
      const int h = blockIdx.y;
      float p[4];
      #pragma unroll
      for (int i = 0; i < 4; ++i)
        p[i] = acc[i][0] * att[h * 128 + c0 + 0] + acc[i][1] * att[h * 128 + c0 + 1] +
               acc[i][2] * att[h * 128 + c0 + 2] + acc[i][3] * att[h * 128 + c0 + 3];
      #pragma unroll
      for (int m = 1; m < 16; m <<= 1) {
        #pragma unroll
        for (int i = 0; i < 4; ++i) p[i] += __shfl_xor(p[i], m);
      }
      if (tx == 0) {
        #pragma unroll
        for (int i = 0; i < 4; ++i) {
          long gr = row0 + r0 + i;
          if (gr < n) sal[gr * NH + h] = p[i];
        }
      }
    }
  }
}

// ---------- GCN aggregate via CSR (wave per node, lane = channel) ----------
__global__ __launch_bounds__(256)
void k_gcn_csr(const int* __restrict__ goff, const int* __restrict__ gcsr,
               const float* __restrict__ h, const float* __restrict__ dinv,
               const float* __restrict__ bg, float* __restrict__ xpj, int n) {
  const int lane = threadIdx.x & 63;
  const int d = blockIdx.x * 4 + (threadIdx.x >> 6);
  if (d >= n) return;
  const int o0 = goff[d], o1 = goff[d + 1];
  float acc = 0.f;
  for (int j = o0; j < o1; ++j) {
    int s = gcsr[j];
    acc = fmaf(h[(long)s * 64 + lane], dinv[s], acc);
  }
  float di = dinv[d];
  xpj[(long)d * 64 + lane] = bg[lane] + di * acc + h[(long)d * 64 + lane] * di * di;
}

// ---------- fused attention mega-kernel (wave per node, bf16 h2 gathers) ----------
__global__ __launch_bounds__(256)
void k_mega(const int* __restrict__ soff, const int* __restrict__ scsr,
            const unsigned short* __restrict__ h2b, const float* __restrict__ sal,
            const float* __restrict__ att, float* __restrict__ xm, int n) {
  const int lane = threadIdx.x & 63;
  const int d = blockIdx.x * 4 + (threadIdx.x >> 6);
  if (d >= n) return;
  const int o0 = soff[d], o1 = soff[d + 1];

  float attj[NH];
  #pragma unroll
  for (int h = 0; h < NH; ++h) attj[h] = att[h * 128 + 64 + lane];

  // Pass 1: per-channel max over neighbor h2 rows (registers only)
  float hm[NH];
  #pragma unroll
  for (int h = 0; h < NH; ++h) hm[h] = -INFINITY;
  for (int j = o0; j < o1; ++j) {
    long s = scsr[j];
    #pragma unroll
    for (int h = 0; h < NH; ++h)
      hm[h] = fmaxf(hm[h], bf2f(h2b[s * 384 + h * 64 + lane]));
  }
  float dal[NH];
  #pragma unroll
  for (int h = 0; h < NH; ++h) dal[h] = wave_sum64(hm[h] * attj[h]);

  // Pass 2: per-head max of alpha over this node's edges (lane = edge)
  float mx[NH];
  #pragma unroll
  for (int h = 0; h < NH; ++h) mx[h] = -INFINITY;
  for (int base = o0; base < o1; base += 64) {
    int j = base + lane;
    float a6[NH];
    if (j < o1) {
      long s = scsr[j];
      #pragma unroll
      for (int h = 0; h < NH; ++h) {
        float al = sal[s * NH + h] + dal[h];
        a6[h] = (al >= 0.f) ? al : NEG_SLOPE * al;
      }
    } else {
      #pragma unroll
      for (int h = 0; h < NH; ++h) a6[h] = -INFINITY;
    }
    #pragma unroll
    for (int h = 0; h < NH; ++h) mx[h] = fmaxf(mx[h], wave_max64(a6[h]));
  }

  // Pass 3: exp / denom, then per-head weighted aggregation (lane = channel)
  float den[NH], acc[NH];
  #pragma unroll
  for (int h = 0; h < NH; ++h) { den[h] = 0.f; acc[h] = 0.f; }
  for (int base = o0; base < o1; base += 64) {
    int cs = o1 - base; if (cs > 64) cs = 64;
    int j = base + lane;
    float e6[NH];
    int s = 0;
    if (j < o1) {
      s = scsr[j];
      #pragma unroll
      for (int h = 0; h < NH; ++h) {
        float al = sal[(long)s * NH + h] + dal[h];
        al = (al >= 0.f) ? al : NEG_SLOPE * al;
        e6[h] = expf(al - mx[h]);
      }
    } else {
      #pragma unroll
      for (int h = 0; h < NH; ++h) e6[h] = 0.f;
    }
    #pragma unroll
    for (int h = 0; h < NH; ++h) den[h] += wave_sum64(e6[h]);
    for (int jj = 0; jj < cs; ++jj) {
      long sj = __shfl(s, jj);
      #pragma unroll
      for (int h = 0; h < NH; ++h) {
        float w = __shfl(e6[h], jj);
        acc[h] = fmaf(bf2f(h2b[sj * 384 + h * 64 + lane]), w, acc[h]);
      }
    }
  }
  float o = 0.f;
  #pragma unroll
  for (int h = 0; h < NH; ++h) o += acc[h] / den[h];
  xm[(long)d * 64 + lane] = o * (1.0f / NH);
}

// bsc = xm@W2 + b2 ; a <- a / max(||a||, EPS)   (wave per node)
__global__ __launch_bounds__(256)
void k_node_fin(const float* __restrict__ xm, float* __restrict__ a,
                const float* __restrict__ W2, const float* __restrict__ b2,
                float* __restrict__ bsc, int n) {
  const int lane = threadIdx.x & 63;
  const int i = blockIdx.x * 4 + (threadIdx.x >> 6);
  if (i >= n) return;
  float xv = xm[(long)i * 64 + lane];
  float av = a[(long)i * 64 + lane];
  float dot = wave_sum64(xv * W2[lane]);
  float ss  = wave_sum64(av * av);
  float nrm = fmaxf(sqrtf(ss), COS_EPS);
  a[(long)i * 64 + lane] = av / nrm;
  if (lane == 0) bsc[i] = dot + b2[0];
}

// fitness[d] = sigmoid(bsc[d] * sum_j dot(an[s_j], an[d]))   (wave per node)
__global__ __launch_bounds__(256)
void k_cosout(const int* __restrict__ soff, const int* __restrict__ scsr,
              const float* __restrict__ an, const float* __restrict__ bsc,
              float* __restrict__ out, int n) {
  const int lane = threadIdx.x & 63;
  const int d = blockIdx.x * 4 + (threadIdx.x >> 6);
  if (d >= n) return;
  const int o0 = soff[d], o1 = soff[d + 1];
  float ad = an[(long)d * 64 + lane];
  float cs = 0.f;
  for (int j = o0; j < o1; ++j) {
    long s = scsr[j];
    cs += wave_sum64(ad * an[s * 64 + lane]);
  }
  if (lane == 0) {
    float sc = bsc[d] * cs;
    out[d] = 1.0f / (1.0f + expf(-sc));
  }
}

// ---------- launcher ----------
static inline unsigned gsblocks(long total) {
  long b = (total + TPB - 1) / TPB;
  if (b > 131072) b = 131072;
  return (unsigned)b;
}

extern "C" void kernel_launch(void* const* d_in, const int* in_sizes, int n_in,
                              void* d_out, int out_size, void* d_ws, size_t ws_size,
                              hipStream_t stream) {
  const float* x   = (const float*)d_in[0];
  const float* Wg  = (const float*)d_in[1];
  const float* bg  = (const float*)d_in[2];
  const float* Wt  = (const float*)d_in[3];
  const float* att = (const float*)d_in[4];
  const float* W1  = (const float*)d_in[5];
  const float* W2  = (const float*)d_in[6];
  const float* b2  = (const float*)d_in[7];
  const int* src   = (const int*)d_in[8];
  const int* dst   = (const int*)d_in[9];
  const int* ssrc  = (const int*)d_in[10];
  const int* sdst  = (const int*)d_in[11];

  const long n   = in_sizes[0] / 64;   // 50000
  const long en  = in_sizes[8];        // E + N
  const long sen = in_sizes[10];       // N + E

  char* base = (char*)d_ws;
  size_t off = 0;
  auto alloc = [&](size_t bytes) -> void* {
    void* p = base + off;
    off += (bytes + 255) & ~(size_t)255;
    return p;
  };
  int*   gcnt = (int*)alloc(n * 4);
  int*   scnt = (int*)alloc(n * 4);   // contiguous with gcnt (one memset covers both)
  int*   goff = (int*)alloc((n + 1) * 4);
  int*   soff = (int*)alloc((n + 1) * 4);
  int*   gcur = (int*)alloc(n * 4);
  int*   scur = (int*)alloc(n * 4);
  int*   gcsr = (int*)alloc(en * 4);
  int*   scsr = (int*)alloc(sen * 4);
  float* dinv = (float*)alloc(n * 4);
  float* h    = (float*)alloc(n * 64 * 4);       // later: xm
  float* xpj  = (float*)alloc(n * 64 * 4);       // later: a
  unsigned short* h2b = (unsigned short*)alloc(n * 384 * 2);
  float* sal  = (float*)alloc(n * NH * 4);
  float* bsc  = (float*)alloc(n * 4);
  float* xm   = h;     // alias: h dead after k_gcn_csr
  float* a    = xpj;   // alias: xpj dead after h2 GEMM
  float* out  = (float*)d_out;

  const unsigned rowblk  = (unsigned)((n + 63) / 64);
  const unsigned nodeblk = (unsigned)((n + 3) / 4);

  // ---- CSR build (both graphs) ----
  hipMemsetAsync(gcnt, 0, (size_t)((char*)scnt - (char*)gcnt) + n * 4, stream);
  k_cnt<<<gsblocks(en), TPB, 0, stream>>>(dst, sdst, gcnt, scnt, en, sen);
  k_dinv<<<gsblocks(n), TPB, 0, stream>>>(gcnt, dinv, n);
  k_scan2<<<2, 1024, 0, stream>>>(gcnt, goff, gcur, scnt, soff, scur, (int)n);
  k_scatter<<<gsblocks(en), TPB, 0, stream>>>(src, dst, ssrc, sdst,
                                              gcur, gcsr, scur, scsr, en, sen);

  // ---- h = x @ W_gcn (fp32) ----
  { dim3 g(rowblk, 1);
    k_gemm64v2<<<g, 256, 0, stream>>>(x, Wg, h, nullptr, nullptr, nullptr, (int)n, 64); }

  // ---- xpj = GCN(h) via CSR ----
  k_gcn_csr<<<nodeblk, 256, 0, stream>>>(goff, gcsr, h, dinv, bg, xpj, (int)n);

  // ---- h2 = xpj @ weight (bf16 out) + fused sal (fp32) ----
  { dim3 g(rowblk, 6);
    k_gemm64v2<<<g, 256, 0, stream>>>(xpj, Wt, nullptr, h2b, att, sal, (int)n, 384); }

  // ---- fused attention (hmax+alpha+softmax+aggregate) -> xm ----
  k_mega<<<nodeblk, 256, 0, stream>>>(soff, scsr, h2b, sal, att, xm, (int)n);

  // ---- a = xm @ W1 (fp32) ----
  { dim3 g(rowblk, 1);
    k_gemm64v2<<<g, 256, 0, stream>>>(xm, W1, a, nullptr, nullptr, nullptr, (int)n, 64); }

  // ---- bsc + normalize a ----
  k_node_fin<<<nodeblk, 256, 0, stream>>>(xm, a, W2, b2, bsc, (int)n);

  // ---- cosine + sigmoid -> out ----
  k_cosout<<<nodeblk, 256, 0, stream>>>(soff, scsr, a, bsc, out, (int)n);
}

// Round 6
// 453.278 us; speedup vs baseline: 3.1744x; 1.1356x over previous
//
#include <hip/hip_runtime.h>
#include <math.h>

#define TPB 256
#define NEG_SLOPE 0.2f
#define COS_EPS 1e-8f
#define NH 6
#define GSTRIDE 68   // LDS row stride (floats) for GEMM tiles
#define DCACHE 12    // neighbor rows cached in registers per node
#define SALS 8       // sal row stride (floats), 32B-aligned

// ---------- helpers ----------
__device__ inline float wave_sum64(float v) {
  #pragma unroll
  for (int off = 32; off > 0; off >>= 1) v += __shfl_down(v, off);
  return __shfl(v, 0);
}
__device__ inline float wave_max64(float v) {
  #pragma unroll
  for (int off = 32; off > 0; off >>= 1) v = fmaxf(v, __shfl_down(v, off));
  return __shfl(v, 0);
}
__device__ inline unsigned short f2bf(float f) {
  unsigned u = __float_as_uint(f);
  unsigned r = (u + 0x7fffu + ((u >> 16) & 1u)) >> 16;   // RNE
  return (unsigned short)r;
}
__device__ inline float bf2f(unsigned short b) {
  return __uint_as_float(((unsigned)b) << 16);
}
// packed bf16 pair (low = even head, high = odd head)
__device__ inline float bflo(unsigned u) { return __uint_as_float(u << 16); }
__device__ inline float bfhi(unsigned u) { return __uint_as_float(u & 0xffff0000u); }

#define GS_LOOP(i, total) \
  for (long i = (long)blockIdx.x * blockDim.x + threadIdx.x; i < (total); \
       i += (long)gridDim.x * blockDim.x)

// ---------- CSR build ----------
__global__ void k_cnt(const int* __restrict__ dst, const int* __restrict__ sdst,
                      int* __restrict__ gcnt, int* __restrict__ scnt,
                      long en, long sen) {
  long mx = en > sen ? en : sen;
  GS_LOOP(e, mx) {
    if (e < en)  atomicAdd(&gcnt[dst[e]], 1);
    if (e < sen) atomicAdd(&scnt[sdst[e]], 1);
  }
}

// phase A: per-tile sums (2048 elems/block) + dinv (g-array blocks only)
__global__ __launch_bounds__(1024)
void k_scanA(const int* __restrict__ gcnt, const int* __restrict__ scnt,
             int* __restrict__ bsum, float* __restrict__ dinv, int n, int nb) {
  const int b = blockIdx.x;
  const bool isS = b >= nb;
  const int tb = isS ? b - nb : b;
  const int* cnt = isS ? scnt : gcnt;
  const int t = threadIdx.x;
  const int i0 = tb * 2048 + 2 * t;
  int v0 = (i0 < n) ? cnt[i0] : 0;
  int v1 = (i0 + 1 < n) ? cnt[i0 + 1] : 0;
  if (!isS) {
    if (i0 < n)     dinv[i0]     = rsqrtf((float)v0 + 1.0f);
    if (i0 + 1 < n) dinv[i0 + 1] = rsqrtf((float)v1 + 1.0f);
  }
  __shared__ int red[16];
  int x = v0 + v1;
  #pragma unroll
  for (int o = 32; o > 0; o >>= 1) x += __shfl_down(x, o);
  const int lane = t & 63, wv = t >> 6;
  if (lane == 0) red[wv] = x;
  __syncthreads();
  if (t < 64) {
    int w = (t < 16) ? red[t] : 0;
    #pragma unroll
    for (int o = 32; o > 0; o >>= 1) w += __shfl_down(w, o);
    if (t == 0) bsum[b] = w;
  }
}

// phase B: exclusive-scan the two halves of bsum (nb each)
__global__ void k_scanB(int* __restrict__ bsum, int nb) {
  const int lane = threadIdx.x;   // 64 threads
  if (nb <= 32) {
    int half = lane >> 5, idx = lane & 31;
    int base = half * nb;
    int v = (idx < nb) ? bsum[base + idx] : 0;
    int orig = v;
    #pragma unroll
    for (int d2 = 1; d2 < 32; d2 <<= 1) {
      int y = __shfl_up(v, d2, 32);
      if (idx >= d2) v += y;
    }
    if (idx < nb) bsum[base + idx] = v - orig;
  } else if (lane == 0) {
    int run = 0;
    for (int i = 0; i < nb; ++i) { int v = bsum[i]; bsum[i] = run; run += v; }
    run = 0;
    for (int i = 0; i < nb; ++i) { int v = bsum[nb + i]; bsum[nb + i] = run; run += v; }
  }
}

// phase C: per-tile scan + writeback of off/cur
__global__ __launch_bounds__(1024)
void k_scanC(const int* __restrict__ gcnt, int* __restrict__ goff, int* __restrict__ gcur,
             const int* __restrict__ scnt, int* __restrict__ soff, int* __restrict__ scur,
             const int* __restrict__ bsum, int n, int nb) {
  const int b = blockIdx.x;
  const bool isS = b >= nb;
  const int tb = isS ? b - nb : b;
  const int* cnt = isS ? scnt : gcnt;
  int* off = isS ? soff : goff;
  int* cur = isS ? scur : gcur;
  const int t = threadIdx.x;
  const int i0 = tb * 2048 + 2 * t;
  int v0 = (i0 < n) ? cnt[i0] : 0;
  int v1 = (i0 + 1 < n) ? cnt[i0 + 1] : 0;
  int s2 = v0 + v1;
  const int lane = t & 63, wv = t >> 6;
  int x = s2;
  #pragma unroll
  for (int d2 = 1; d2 < 64; d2 <<= 1) {
    int y = __shfl_up(x, d2);
    if (lane >= d2) x += y;
  }
  __shared__ int wsum[16];
  if (lane == 63) wsum[wv] = x;
  __syncthreads();
  if (t < 64) {
    int w = (t < 16) ? wsum[t] : 0;
    #pragma unroll
    for (int d2 = 1; d2 < 16; d2 <<= 1) {
      int y = __shfl_up(w, d2);
      if ((int)t >= d2) w += y;
    }
    if (t < 16) wsum[t] = w;
  }
  __syncthreads();
  int ex = x - s2 + (wv ? wsum[wv - 1] : 0) + bsum[b];
  if (i0 < n)     { cur[i0] = ex;          off[i0 + 1] = ex + v0; }
  if (i0 + 1 < n) { cur[i0 + 1] = ex + v0; off[i0 + 2] = ex + v0 + v1; }
  if (i0 == 0) off[0] = 0;
}

__global__ void k_scatter(const int* __restrict__ src, const int* __restrict__ dst,
                          const int* __restrict__ ssrc, const int* __restrict__ sdst,
                          int* __restrict__ gcur, int* __restrict__ gcsr,
                          int* __restrict__ scur, int* __restrict__ scsr,
                          long en, long sen) {
  long mx = en > sen ? en : sen;
  GS_LOOP(e, mx) {
    if (e < en)  { int d = dst[e];  int p = atomicAdd(&gcur[d], 1); gcsr[p] = src[e]; }
    if (e < sen) { int d = sdst[e]; int p = atomicAdd(&scur[d], 1); scsr[p] = ssrc[e]; }
  }
}

// ---------- GEMM: A[n][64] @ W[64][Mtot], 64x64 tile, 4x4 reg tile ----------
// MODE 0: fp32 out32.
// MODE 1: bf16 channel-major h2 (out16[r*384 + ch*6 + head]) + fp32 sal[r*SALS+head].
// MODE 2: normalized bf16 rows (out16[r*64+c]) + bsc[r] = A_row·W2 + b2.
template <int MODE>
__global__ __launch_bounds__(256)
void k_gemm64v3(const float* __restrict__ A, const float* __restrict__ W,
                float* __restrict__ out32, unsigned short* __restrict__ out16,
                const float* __restrict__ att, float* __restrict__ sal,
                const float* __restrict__ W2, const float* __restrict__ b2,
                float* __restrict__ bsc, int n, int Mtot) {
  __shared__ float At[64 * GSTRIDE];
  __shared__ float Wl[64 * GSTRIDE];
  const int t  = threadIdx.x;
  const int tx = t & 15;
  const int ty = t >> 4;
  const int col0 = blockIdx.y * 64;
  const long row0 = (long)blockIdx.x * 64;

  #pragma unroll
  for (int i = 0; i < 4; ++i) {
    int k = ty + 16 * i;
    float4 wv = *(const float4*)&W[(long)k * Mtot + col0 + 4 * tx];
    *(float4*)&Wl[k * GSTRIDE + 4 * tx] = wv;
  }
  #pragma unroll
  for (int i = 0; i < 4; ++i) {
    int r = ty + 16 * i;
    long gr = row0 + r; if (gr >= n) gr = n - 1;
    float4 av = *(const float4*)&A[gr * 64 + 4 * tx];
    At[(4 * tx + 0) * GSTRIDE + r] = av.x;
    At[(4 * tx + 1) * GSTRIDE + r] = av.y;
    At[(4 * tx + 2) * GSTRIDE + r] = av.z;
    At[(4 * tx + 3) * GSTRIDE + r] = av.w;
  }
  __syncthreads();

  const int c0 = 4 * tx;
  const int r0 = 4 * ty;
  float acc[4][4] = {};
  #pragma unroll
  for (int k = 0; k < 64; ++k) {
    float4 av = *(const float4*)&At[k * GSTRIDE + r0];
    float4 wv = *(const float4*)&Wl[k * GSTRIDE + c0];
    acc[0][0] = fmaf(av.x, wv.x, acc[0][0]); acc[0][1] = fmaf(av.x, wv.y, acc[0][1]);
    acc[0][2] = fmaf(av.x, wv.z, acc[0][2]); acc[0][3] = fmaf(av.x, wv.w, acc[0][3]);
    acc[1][0] = fmaf(av.y, wv.x, acc[1][0]); acc[1][1] = fmaf(av.y, wv.y, acc[1][1]);
    acc[1][2] = fmaf(av.y, wv.z, acc[1][2]); acc[1][3] = fmaf(av.y, wv.w, acc[1][3]);
    acc[2][0] = fmaf(av.z, wv.x, acc[2][0]); acc[2][1] = fmaf(av.z, wv.y, acc[2][1]);
    acc[2][2] = fmaf(av.z, wv.z, acc[2][2]); acc[2][3] = fmaf(av.z, wv.w, acc[2][3]);
    acc[3][0] = fmaf(av.w, wv.x, acc[3][0]); acc[3][1] = fmaf(av.w, wv.y, acc[3][1]);
    acc[3][2] = fmaf(av.w, wv.z, acc[3][2]); acc[3][3] = fmaf(av.w, wv.w, acc[3][3]);
  }

  if constexpr (MODE == 0) {
    #pragma unroll
    for (int i = 0; i < 4; ++i) {
      long gr = row0 + r0 + i;
      if (gr < n)
        *(float4*)&out32[gr * Mtot + col0 + c0] =
          make_float4(acc[i][0], acc[i][1], acc[i][2], acc[i][3]);
    }
  }
  if constexpr (MODE == 1) {
    const int head = blockIdx.y;
    #pragma unroll
    for (int i = 0; i < 4; ++i) {
      long gr = row0 + r0 + i;
      if (gr < n) {
        #pragma unroll
        for (int j = 0; j < 4; ++j)
          out16[gr * 384 + (c0 + j) * NH + head] = f2bf(acc[i][j]);
      }
    }
    float p[4];
    #pragma unroll
    for (int i = 0; i < 4; ++i)
      p[i] = acc[i][0] * att[head * 128 + c0 + 0] + acc[i][1] * att[head * 128 + c0 + 1] +
             acc[i][2] * att[head * 128 + c0 + 2] + acc[i][3] * att[head * 128 + c0 + 3];
    #pragma unroll
    for (int m = 1; m < 16; m <<= 1) {
      #pragma unroll
      for (int i = 0; i < 4; ++i) p[i] += __shfl_xor(p[i], m);
    }
    if (tx == 0) {
      #pragma unroll
      for (int i = 0; i < 4; ++i) {
        long gr = row0 + r0 + i;
        if (gr < n) sal[gr * SALS + head] = p[i];
      }
    }
  }
  if constexpr (MODE == 2) {
    float p[4], q[4];
    #pragma unroll
    for (int i = 0; i < 4; ++i) {
      q[i] = acc[i][0]*acc[i][0] + acc[i][1]*acc[i][1] +
             acc[i][2]*acc[i][2] + acc[i][3]*acc[i][3];
      p[i] = At[(c0+0) * GSTRIDE + r0 + i] * W2[c0+0] +
             At[(c0+1) * GSTRIDE + r0 + i] * W2[c0+1] +
             At[(c0+2) * GSTRIDE + r0 + i] * W2[c0+2] +
             At[(c0+3) * GSTRIDE + r0 + i] * W2[c0+3];
    }
    #pragma unroll
    for (int m = 1; m < 16; m <<= 1) {
      #pragma unroll
      for (int i = 0; i < 4; ++i) { p[i] += __shfl_xor(p[i], m); q[i] += __shfl_xor(q[i], m); }
    }
    float bb = b2[0];
    #pragma unroll
    for (int i = 0; i < 4; ++i) {
      long gr = row0 + r0 + i;
      if (gr < n) {
        float rn = 1.0f / fmaxf(sqrtf(q[i]), COS_EPS);
        ushort4 v;
        v.x = f2bf(acc[i][0] * rn); v.y = f2bf(acc[i][1] * rn);
        v.z = f2bf(acc[i][2] * rn); v.w = f2bf(acc[i][3] * rn);
        *(ushort4*)&out16[gr * 64 + c0] = v;
        if (tx == 0) bsc[gr] = p[i] + bb;
      }
    }
  }
}

// ---------- GCN aggregate via CSR (wave per node, lane = channel) ----------
__global__ __launch_bounds__(256)
void k_gcn_csr(const int* __restrict__ goff, const int* __restrict__ gcsr,
               const float* __restrict__ h, const float* __restrict__ dinv,
               const float* __restrict__ bg, float* __restrict__ xpj, int n) {
  const int lane = threadIdx.x & 63;
  const int d = blockIdx.x * 4 + (threadIdx.x >> 6);
  if (d >= n) return;
  const int o0 = goff[d], o1 = goff[d + 1];
  float acc = 0.f;
  int j = o0;
  for (; j + 1 < o1; j += 2) {
    int s0 = gcsr[j], s1 = gcsr[j + 1];
    float f0 = h[(long)s0 * 64 + lane], f1 = h[(long)s1 * 64 + lane];
    acc = fmaf(f0, dinv[s0], acc);
    acc = fmaf(f1, dinv[s1], acc);
  }
  if (j < o1) { int s0 = gcsr[j]; acc = fmaf(h[(long)s0 * 64 + lane], dinv[s0], acc); }
  float di = dinv[d];
  xpj[(long)d * 64 + lane] = bg[lane] + di * acc + h[(long)d * 64 + lane] * di * di;
}

// ---------- fused attention mega-kernel (wave per node) ----------
// h2p: channel-major packed bf16 pairs — uint k of row s at [s*192 + lane*3 + k]
// holds heads (2k, 2k+1) of channel `lane`.
__global__ __launch_bounds__(256)
void k_mega(const int* __restrict__ soff, const int* __restrict__ scsr,
            const unsigned* __restrict__ h2p, const float* __restrict__ sal,
            const float* __restrict__ att, float* __restrict__ xm, int n) {
  const int lane = threadIdx.x & 63;
  const int d = blockIdx.x * 4 + (threadIdx.x >> 6);
  if (d >= n) return;
  const int o0 = soff[d], o1 = soff[d + 1];
  const int deg = o1 - o0;

  // ---- pass 1: per-channel hmax + register cache of first DCACHE rows ----
  unsigned ck0[DCACHE], ck1[DCACHE], ck2[DCACHE];
  float hm[NH];
  #pragma unroll
  for (int h = 0; h < NH; ++h) hm[h] = -INFINITY;
  #pragma unroll
  for (int idx = 0; idx < DCACHE; ++idx) {
    unsigned u0 = 0, u1 = 0, u2 = 0;
    if (idx < deg) {
      long s = scsr[o0 + idx];
      const unsigned* rp = &h2p[s * 192 + lane * 3];
      u0 = rp[0]; u1 = rp[1]; u2 = rp[2];
      hm[0] = fmaxf(hm[0], bflo(u0)); hm[1] = fmaxf(hm[1], bfhi(u0));
      hm[2] = fmaxf(hm[2], bflo(u1)); hm[3] = fmaxf(hm[3], bfhi(u1));
      hm[4] = fmaxf(hm[4], bflo(u2)); hm[5] = fmaxf(hm[5], bfhi(u2));
    }
    ck0[idx] = u0; ck1[idx] = u1; ck2[idx] = u2;
  }
  for (int j = o0 + DCACHE; j < o1; ++j) {
    long s = scsr[j];
    const unsigned* rp = &h2p[s * 192 + lane * 3];
    unsigned u0 = rp[0], u1 = rp[1], u2 = rp[2];
    hm[0] = fmaxf(hm[0], bflo(u0)); hm[1] = fmaxf(hm[1], bfhi(u0));
    hm[2] = fmaxf(hm[2], bflo(u1)); hm[3] = fmaxf(hm[3], bfhi(u1));
    hm[4] = fmaxf(hm[4], bflo(u2)); hm[5] = fmaxf(hm[5], bfhi(u2));
  }

  float dal[NH];
  #pragma unroll
  for (int h = 0; h < NH; ++h)
    dal[h] = wave_sum64(hm[h] * att[h * 128 + 64 + lane]);

  float acc[NH], den[NH];
  #pragma unroll
  for (int h = 0; h < NH; ++h) acc[h] = 0.f;

  if (deg <= 64) {
    // ---- fast path: lane = edge softmax, all in one shot ----
    const bool act = lane < deg;
    int sE = 0;
    float4 sA = make_float4(0, 0, 0, 0), sB = sA;
    if (act) {
      sE = scsr[o0 + lane];
      const float4* sp = (const float4*)&sal[(long)sE * SALS];
      sA = sp[0]; sB = sp[1];
    }
    float svv[NH] = {sA.x, sA.y, sA.z, sA.w, sB.x, sB.y};
    float e6[NH];
    #pragma unroll
    for (int h = 0; h < NH; ++h) {
      float al = svv[h] + dal[h];
      al = (al >= 0.f) ? al : NEG_SLOPE * al;
      float a = act ? al : -INFINITY;
      float mx = wave_max64(a);
      e6[h] = act ? expf(a - mx) : 0.f;
      den[h] = wave_sum64(e6[h]);
    }
    // aggregate cached rows
    #pragma unroll
    for (int idx = 0; idx < DCACHE; ++idx) {
      if (idx < deg) {
        float w0 = __shfl(e6[0], idx), w1 = __shfl(e6[1], idx);
        float w2 = __shfl(e6[2], idx), w3 = __shfl(e6[3], idx);
        float w4 = __shfl(e6[4], idx), w5 = __shfl(e6[5], idx);
        acc[0] = fmaf(bflo(ck0[idx]), w0, acc[0]);
        acc[1] = fmaf(bfhi(ck0[idx]), w1, acc[1]);
        acc[2] = fmaf(bflo(ck1[idx]), w2, acc[2]);
        acc[3] = fmaf(bfhi(ck1[idx]), w3, acc[3]);
        acc[4] = fmaf(bflo(ck2[idx]), w4, acc[4]);
        acc[5] = fmaf(bfhi(ck2[idx]), w5, acc[5]);
      }
    }
    // overflow edges (DCACHE < deg <= 64): re-read rows
    for (int j = o0 + DCACHE; j < o1; ++j) {
      int ii = j - o0;
      long s = scsr[j];
      const unsigned* rp = &h2p[s * 192 + lane * 3];
      unsigned u0 = rp[0], u1 = rp[1], u2 = rp[2];
      float w0 = __shfl(e6[0], ii), w1 = __shfl(e6[1], ii);
      float w2 = __shfl(e6[2], ii), w3 = __shfl(e6[3], ii);
      float w4 = __shfl(e6[4], ii), w5 = __shfl(e6[5], ii);
      acc[0] = fmaf(bflo(u0), w0, acc[0]);
      acc[1] = fmaf(bfhi(u0), w1, acc[1]);
      acc[2] = fmaf(bflo(u1), w2, acc[2]);
      acc[3] = fmaf(bfhi(u1), w3, acc[3]);
      acc[4] = fmaf(bflo(u2), w4, acc[4]);
      acc[5] = fmaf(bfhi(u2), w5, acc[5]);
    }
  } else {
    // ---- slow path (deg > 64): base-block loops, no cache ----
    float mx[NH];
    #pragma unroll
    for (int h = 0; h < NH; ++h) { mx[h] = -INFINITY; den[h] = 0.f; }
    for (int base = o0; base < o1; base += 64) {
      int j = base + lane;
      float a6[NH];
      if (j < o1) {
        long s = scsr[j];
        const float4* sp = (const float4*)&sal[s * SALS];
        float4 sA = sp[0], sB = sp[1];
        float svv[NH] = {sA.x, sA.y, sA.z, sA.w, sB.x, sB.y};
        #pragma unroll
        for (int h = 0; h < NH; ++h) {
          float al = svv[h] + dal[h];
          a6[h] = (al >= 0.f) ? al : NEG_SLOPE * al;
        }
      } else {
        #pragma unroll
        for (int h = 0; h < NH; ++h) a6[h] = -INFINITY;
      }
      #pragma unroll
      for (int h = 0; h < NH; ++h) mx[h] = fmaxf(mx[h], wave_max64(a6[h]));
    }
    for (int base = o0; base < o1; base += 64) {
      int cs = o1 - base; if (cs > 64) cs = 64;
      int j = base + lane;
      float e6[NH]; int s = 0;
      if (j < o1) {
        s = scsr[j];
        const float4* sp = (const float4*)&sal[(long)s * SALS];
        float4 sA = sp[0], sB = sp[1];
        float svv[NH] = {sA.x, sA.y, sA.z, sA.w, sB.x, sB.y};
        #pragma unroll
        for (int h = 0; h < NH; ++h) {
          float al = svv[h] + dal[h];
          al = (al >= 0.f) ? al : NEG_SLOPE * al;
          e6[h] = expf(al - mx[h]);
        }
      } else {
        #pragma unroll
        for (int h = 0; h < NH; ++h) e6[h] = 0.f;
      }
      #pragma unroll
      for (int h = 0; h < NH; ++h) den[h] += wave_sum64(e6[h]);
      for (int jj = 0; jj < cs; ++jj) {
        int sj = __shfl(s, jj);
        const unsigned* rp = &h2p[(long)sj * 192 + lane * 3];
        unsigned u0 = rp[0], u1 = rp[1], u2 = rp[2];
        float w0 = __shfl(e6[0], jj), w1 = __shfl(e6[1], jj);
        float w2 = __shfl(e6[2], jj), w3 = __shfl(e6[3], jj);
        float w4 = __shfl(e6[4], jj), w5 = __shfl(e6[5], jj);
        acc[0] = fmaf(bflo(u0), w0, acc[0]);
        acc[1] = fmaf(bfhi(u0), w1, acc[1]);
        acc[2] = fmaf(bflo(u1), w2, acc[2]);
        acc[3] = fmaf(bfhi(u1), w3, acc[3]);
        acc[4] = fmaf(bflo(u2), w4, acc[4]);
        acc[5] = fmaf(bfhi(u2), w5, acc[5]);
      }
    }
  }

  float o = 0.f;
  #pragma unroll
  for (int h = 0; h < NH; ++h) o += acc[h] / den[h];
  xm[(long)d * 64 + lane] = o * (1.0f / NH);
}

// fitness[d] = sigmoid(bsc[d] * sum_j dot(an[s_j], an[d]))  (wave per node, bf16 an)
__global__ __launch_bounds__(256)
void k_cosout(const int* __restrict__ soff, const int* __restrict__ scsr,
              const unsigned short* __restrict__ an, const float* __restrict__ bsc,
              float* __restrict__ out, int n) {
  const int lane = threadIdx.x & 63;
  const int d = blockIdx.x * 4 + (threadIdx.x >> 6);
  if (d >= n) return;
  const int o0 = soff[d], o1 = soff[d + 1];
  float ad = bf2f(an[(long)d * 64 + lane]);
  float cl = 0.f;
  int j = o0;
  for (; j + 1 < o1; j += 2) {
    int s0 = scsr[j], s1 = scsr[j + 1];
    float f0 = bf2f(an[(long)s0 * 64 + lane]);
    float f1 = bf2f(an[(long)s1 * 64 + lane]);
    cl = fmaf(ad, f0, cl);
    cl = fmaf(ad, f1, cl);
  }
  if (j < o1) { int s0 = scsr[j]; cl = fmaf(ad, bf2f(an[(long)s0 * 64 + lane]), cl); }
  float cs = wave_sum64(cl);
  if (lane == 0) out[d] = 1.0f / (1.0f + expf(-bsc[d] * cs));
}

// ---------- launcher ----------
static inline unsigned gsblocks(long total) {
  long b = (total + TPB - 1) / TPB;
  if (b > 131072) b = 131072;
  return (unsigned)b;
}

extern "C" void kernel_launch(void* const* d_in, const int* in_sizes, int n_in,
                              void* d_out, int out_size, void* d_ws, size_t ws_size,
                              hipStream_t stream) {
  const float* x   = (const float*)d_in[0];
  const float* Wg  = (const float*)d_in[1];
  const float* bg  = (const float*)d_in[2];
  const float* Wt  = (const float*)d_in[3];
  const float* att = (const float*)d_in[4];
  const float* W1  = (const float*)d_in[5];
  const float* W2  = (const float*)d_in[6];
  const float* b2  = (const float*)d_in[7];
  const int* src   = (const int*)d_in[8];
  const int* dst   = (const int*)d_in[9];
  const int* ssrc  = (const int*)d_in[10];
  const int* sdst  = (const int*)d_in[11];

  const long n   = in_sizes[0] / 64;   // 50000
  const long en  = in_sizes[8];        // E + N
  const long sen = in_sizes[10];       // N + E
  const int  nb  = (int)((n + 2047) / 2048);

  char* base = (char*)d_ws;
  size_t off = 0;
  auto alloc = [&](size_t bytes) -> void* {
    void* p = base + off;
    off += (bytes + 255) & ~(size_t)255;
    return p;
  };
  int*   gcnt = (int*)alloc(n * 4);
  int*   scnt = (int*)alloc(n * 4);   // contiguous with gcnt (one memset)
  int*   goff = (int*)alloc((n + 1) * 4);
  int*   soff = (int*)alloc((n + 1) * 4);
  int*   gcur = (int*)alloc(n * 4);
  int*   scur = (int*)alloc(n * 4);
  int*   gcsr = (int*)alloc(en * 4);
  int*   scsr = (int*)alloc(sen * 4);
  int*   bsum = (int*)alloc(2 * (size_t)nb * 4);
  float* dinv = (float*)alloc(n * 4);
  float* h    = (float*)alloc(n * 64 * 4);            // later: xm
  float* xpj  = (float*)alloc(n * 64 * 4);            // later: anorm (bf16)
  unsigned* h2p = (unsigned*)alloc(n * 192 * 4);      // channel-major bf16 pairs
  float* sal  = (float*)alloc(n * SALS * 4);
  float* bsc  = (float*)alloc(n * 4);
  float* xm   = h;                                    // alias
  unsigned short* anorm = (unsigned short*)xpj;       // alias
  float* out  = (float*)d_out;

  const unsigned rowblk  = (unsigned)((n + 63) / 64);
  const unsigned nodeblk = (unsigned)((n + 3) / 4);

  // ---- CSR build (both graphs) + dinv ----
  hipMemsetAsync(gcnt, 0, (size_t)((char*)scnt - (char*)gcnt) + n * 4, stream);
  k_cnt<<<gsblocks(en), TPB, 0, stream>>>(dst, sdst, gcnt, scnt, en, sen);
  k_scanA<<<2 * nb, 1024, 0, stream>>>(gcnt, scnt, bsum, dinv, (int)n, nb);
  k_scanB<<<1, 64, 0, stream>>>(bsum, nb);
  k_scanC<<<2 * nb, 1024, 0, stream>>>(gcnt, goff, gcur, scnt, soff, scur,
                                       bsum, (int)n, nb);
  k_scatter<<<gsblocks(en), TPB, 0, stream>>>(src, dst, ssrc, sdst,
                                              gcur, gcsr, scur, scsr, en, sen);

  // ---- h = x @ W_gcn (fp32) ----
  { dim3 g(rowblk, 1);
    k_gemm64v3<0><<<g, 256, 0, stream>>>(x, Wg, h, nullptr, nullptr, nullptr,
                                         nullptr, nullptr, nullptr, (int)n, 64); }

  // ---- xpj = GCN(h) via CSR ----
  k_gcn_csr<<<nodeblk, 256, 0, stream>>>(goff, gcsr, h, dinv, bg, xpj, (int)n);

  // ---- h2 = xpj @ weight (bf16 channel-major) + fused sal ----
  { dim3 g(rowblk, 6);
    k_gemm64v3<1><<<g, 256, 0, stream>>>(xpj, Wt, nullptr, (unsigned short*)h2p,
                                         att, sal, nullptr, nullptr, nullptr,
                                         (int)n, 384); }

  // ---- fused attention -> xm (aliases h) ----
  k_mega<<<nodeblk, 256, 0, stream>>>(soff, scsr, h2p, sal, att, xm, (int)n);

  // ---- a = normalize(xm @ W1) (bf16, aliases xpj) + bsc, fused epilogue ----
  { dim3 g(rowblk, 1);
    k_gemm64v3<2><<<g, 256, 0, stream>>>(xm, W1, nullptr, anorm, nullptr, nullptr,
                                         W2, b2, bsc, (int)n, 64); }

  // ---- cosine + sigmoid -> out ----
  k_cosout<<<nodeblk, 256, 0, stream>>>(soff, scsr, anorm, bsc, out, (int)n);
}

// Round 7
// 375.126 us; speedup vs baseline: 3.8358x; 1.2083x over previous
//
#include <hip/hip_runtime.h>
#include <math.h>

#define TPB 256
#define NEG_SLOPE 0.2f
#define COS_EPS 1e-8f
#define NH 6
#define GSTRIDE 68   // LDS row stride (floats) for GEMM tiles
#define DCACHE 12    // neighbor rows cached in registers per node
#define SALS 8       // sal row stride (floats), 32B-aligned

// ---------- helpers ----------
__device__ inline float wave_sum64(float v) {
  #pragma unroll
  for (int off = 32; off > 0; off >>= 1) v += __shfl_down(v, off);
  return __shfl(v, 0);
}
__device__ inline float wave_max64(float v) {
  #pragma unroll
  for (int off = 32; off > 0; off >>= 1) v = fmaxf(v, __shfl_down(v, off));
  return __shfl(v, 0);
}
__device__ inline unsigned short f2bf(float f) {
  unsigned u = __float_as_uint(f);
  unsigned r = (u + 0x7fffu + ((u >> 16) & 1u)) >> 16;   // RNE
  return (unsigned short)r;
}
__device__ inline float bf2f(unsigned short b) {
  return __uint_as_float(((unsigned)b) << 16);
}
__device__ inline unsigned packbf(float lo, float hi) {
  return (unsigned)f2bf(lo) | ((unsigned)f2bf(hi) << 16);
}
// packed bf16 pair (low = even head, high = odd head)
__device__ inline float bflo(unsigned u) { return __uint_as_float(u << 16); }
__device__ inline float bfhi(unsigned u) { return __uint_as_float(u & 0xffff0000u); }

#define GS_LOOP(i, total) \
  for (long i = (long)blockIdx.x * blockDim.x + threadIdx.x; i < (total); \
       i += (long)gridDim.x * blockDim.x)

// ---------- CSR build ----------
__global__ void k_cnt(const int* __restrict__ dst, const int* __restrict__ sdst,
                      int* __restrict__ gcnt, int* __restrict__ scnt,
                      long en, long sen) {
  long mx = en > sen ? en : sen;
  GS_LOOP(e, mx) {
    if (e < en)  atomicAdd(&gcnt[dst[e]], 1);
    if (e < sen) atomicAdd(&scnt[sdst[e]], 1);
  }
}

// phase A: per-tile sums (2048 elems/block) + dinv (g-array blocks only)
__global__ __launch_bounds__(1024)
void k_scanA(const int* __restrict__ gcnt, const int* __restrict__ scnt,
             int* __restrict__ bsum, float* __restrict__ dinv, int n, int nb) {
  const int b = blockIdx.x;
  const bool isS = b >= nb;
  const int tb = isS ? b - nb : b;
  const int* cnt = isS ? scnt : gcnt;
  const int t = threadIdx.x;
  const int i0 = tb * 2048 + 2 * t;
  int v0 = (i0 < n) ? cnt[i0] : 0;
  int v1 = (i0 + 1 < n) ? cnt[i0 + 1] : 0;
  if (!isS) {
    if (i0 < n)     dinv[i0]     = rsqrtf((float)v0 + 1.0f);
    if (i0 + 1 < n) dinv[i0 + 1] = rsqrtf((float)v1 + 1.0f);
  }
  __shared__ int red[16];
  int x = v0 + v1;
  #pragma unroll
  for (int o = 32; o > 0; o >>= 1) x += __shfl_down(x, o);
  const int lane = t & 63, wv = t >> 6;
  if (lane == 0) red[wv] = x;
  __syncthreads();
  if (t < 64) {
    int w = (t < 16) ? red[t] : 0;
    #pragma unroll
    for (int o = 32; o > 0; o >>= 1) w += __shfl_down(w, o);
    if (t == 0) bsum[b] = w;
  }
}

// phase B: exclusive-scan the two halves of bsum (nb each)
__global__ void k_scanB(int* __restrict__ bsum, int nb) {
  const int lane = threadIdx.x;   // 64 threads
  if (nb <= 32) {
    int half = lane >> 5, idx = lane & 31;
    int base = half * nb;
    int v = (idx < nb) ? bsum[base + idx] : 0;
    int orig = v;
    #pragma unroll
    for (int d2 = 1; d2 < 32; d2 <<= 1) {
      int y = __shfl_up(v, d2, 32);
      if (idx >= d2) v += y;
    }
    if (idx < nb) bsum[base + idx] = v - orig;
  } else if (lane == 0) {
    int run = 0;
    for (int i = 0; i < nb; ++i) { int v = bsum[i]; bsum[i] = run; run += v; }
    run = 0;
    for (int i = 0; i < nb; ++i) { int v = bsum[nb + i]; bsum[nb + i] = run; run += v; }
  }
}

// phase C: per-tile scan + writeback of off/cur
__global__ __launch_bounds__(1024)
void k_scanC(const int* __restrict__ gcnt, int* __restrict__ goff, int* __restrict__ gcur,
             const int* __restrict__ scnt, int* __restrict__ soff, int* __restrict__ scur,
             const int* __restrict__ bsum, int n, int nb) {
  const int b = blockIdx.x;
  const bool isS = b >= nb;
  const int tb = isS ? b - nb : b;
  const int* cnt = isS ? scnt : gcnt;
  int* off = isS ? soff : goff;
  int* cur = isS ? scur : gcur;
  const int t = threadIdx.x;
  const int i0 = tb * 2048 + 2 * t;
  int v0 = (i0 < n) ? cnt[i0] : 0;
  int v1 = (i0 + 1 < n) ? cnt[i0 + 1] : 0;
  int s2 = v0 + v1;
  const int lane = t & 63, wv = t >> 6;
  int x = s2;
  #pragma unroll
  for (int d2 = 1; d2 < 64; d2 <<= 1) {
    int y = __shfl_up(x, d2);
    if (lane >= d2) x += y;
  }
  __shared__ int wsum[16];
  if (lane == 63) wsum[wv] = x;
  __syncthreads();
  if (t < 64) {
    int w = (t < 16) ? wsum[t] : 0;
    #pragma unroll
    for (int d2 = 1; d2 < 16; d2 <<= 1) {
      int y = __shfl_up(w, d2);
      if ((int)t >= d2) w += y;
    }
    if (t < 16) wsum[t] = w;
  }
  __syncthreads();
  int ex = x - s2 + (wv ? wsum[wv - 1] : 0) + bsum[b];
  if (i0 < n)     { cur[i0] = ex;          off[i0 + 1] = ex + v0; }
  if (i0 + 1 < n) { cur[i0 + 1] = ex + v0; off[i0 + 2] = ex + v0 + v1; }
  if (i0 == 0) off[0] = 0;
}

__global__ void k_scatter(const int* __restrict__ src, const int* __restrict__ dst,
                          const int* __restrict__ ssrc, const int* __restrict__ sdst,
                          int* __restrict__ gcur, int* __restrict__ gcsr,
                          int* __restrict__ scur, int* __restrict__ scsr,
                          long en, long sen) {
  long mx = en > sen ? en : sen;
  GS_LOOP(e, mx) {
    if (e < en)  { int d = dst[e];  int p = atomicAdd(&gcur[d], 1); gcsr[p] = src[e]; }
    if (e < sen) { int d = sdst[e]; int p = atomicAdd(&scur[d], 1); scsr[p] = ssrc[e]; }
  }
}

// ---------- GEMM: A[n][64] @ W[64][Mtot], 64x64 tile, 4x4 reg tile ----------
// MODE 0: fp32 out32.
// MODE 2: normalized bf16 rows (out16[r*64+c]) + bsc[r] = A_row·W2 + b2.
template <int MODE>
__global__ __launch_bounds__(256)
void k_gemm64v3(const float* __restrict__ A, const float* __restrict__ W,
                float* __restrict__ out32, unsigned short* __restrict__ out16,
                const float* __restrict__ W2, const float* __restrict__ b2,
                float* __restrict__ bsc, int n, int Mtot) {
  __shared__ float At[64 * GSTRIDE];
  __shared__ float Wl[64 * GSTRIDE];
  const int t  = threadIdx.x;
  const int tx = t & 15;
  const int ty = t >> 4;
  const int col0 = blockIdx.y * 64;
  const long row0 = (long)blockIdx.x * 64;

  #pragma unroll
  for (int i = 0; i < 4; ++i) {
    int k = ty + 16 * i;
    float4 wv = *(const float4*)&W[(long)k * Mtot + col0 + 4 * tx];
    *(float4*)&Wl[k * GSTRIDE + 4 * tx] = wv;
  }
  #pragma unroll
  for (int i = 0; i < 4; ++i) {
    int r = ty + 16 * i;
    long gr = row0 + r; if (gr >= n) gr = n - 1;
    float4 av = *(const float4*)&A[gr * 64 + 4 * tx];
    At[(4 * tx + 0) * GSTRIDE + r] = av.x;
    At[(4 * tx + 1) * GSTRIDE + r] = av.y;
    At[(4 * tx + 2) * GSTRIDE + r] = av.z;
    At[(4 * tx + 3) * GSTRIDE + r] = av.w;
  }
  __syncthreads();

  const int c0 = 4 * tx;
  const int r0 = 4 * ty;
  float acc[4][4] = {};
  #pragma unroll
  for (int k = 0; k < 64; ++k) {
    float4 av = *(const float4*)&At[k * GSTRIDE + r0];
    float4 wv = *(const float4*)&Wl[k * GSTRIDE + c0];
    acc[0][0] = fmaf(av.x, wv.x, acc[0][0]); acc[0][1] = fmaf(av.x, wv.y, acc[0][1]);
    acc[0][2] = fmaf(av.x, wv.z, acc[0][2]); acc[0][3] = fmaf(av.x, wv.w, acc[0][3]);
    acc[1][0] = fmaf(av.y, wv.x, acc[1][0]); acc[1][1] = fmaf(av.y, wv.y, acc[1][1]);
    acc[1][2] = fmaf(av.y, wv.z, acc[1][2]); acc[1][3] = fmaf(av.y, wv.w, acc[1][3]);
    acc[2][0] = fmaf(av.z, wv.x, acc[2][0]); acc[2][1] = fmaf(av.z, wv.y, acc[2][1]);
    acc[2][2] = fmaf(av.z, wv.z, acc[2][2]); acc[2][3] = fmaf(av.z, wv.w, acc[2][3]);
    acc[3][0] = fmaf(av.w, wv.x, acc[3][0]); acc[3][1] = fmaf(av.w, wv.y, acc[3][1]);
    acc[3][2] = fmaf(av.w, wv.z, acc[3][2]); acc[3][3] = fmaf(av.w, wv.w, acc[3][3]);
  }

  if constexpr (MODE == 0) {
    #pragma unroll
    for (int i = 0; i < 4; ++i) {
      long gr = row0 + r0 + i;
      if (gr < n)
        *(float4*)&out32[gr * Mtot + col0 + c0] =
          make_float4(acc[i][0], acc[i][1], acc[i][2], acc[i][3]);
    }
  }
  if constexpr (MODE == 2) {
    float p[4], q[4];
    #pragma unroll
    for (int i = 0; i < 4; ++i) {
      q[i] = acc[i][0]*acc[i][0] + acc[i][1]*acc[i][1] +
             acc[i][2]*acc[i][2] + acc[i][3]*acc[i][3];
      p[i] = At[(c0+0) * GSTRIDE + r0 + i] * W2[c0+0] +
             At[(c0+1) * GSTRIDE + r0 + i] * W2[c0+1] +
             At[(c0+2) * GSTRIDE + r0 + i] * W2[c0+2] +
             At[(c0+3) * GSTRIDE + r0 + i] * W2[c0+3];
    }
    #pragma unroll
    for (int m = 1; m < 16; m <<= 1) {
      #pragma unroll
      for (int i = 0; i < 4; ++i) { p[i] += __shfl_xor(p[i], m); q[i] += __shfl_xor(q[i], m); }
    }
    float bb = b2[0];
    #pragma unroll
    for (int i = 0; i < 4; ++i) {
      long gr = row0 + r0 + i;
      if (gr < n) {
        float rn = 1.0f / fmaxf(sqrtf(q[i]), COS_EPS);
        ushort4 v;
        v.x = f2bf(acc[i][0] * rn); v.y = f2bf(acc[i][1] * rn);
        v.z = f2bf(acc[i][2] * rn); v.w = f2bf(acc[i][3] * rn);
        *(ushort4*)&out16[gr * 64 + c0] = v;
        if (tx == 0) bsc[gr] = p[i] + bb;
      }
    }
  }
}

// ---------- h2 GEMM: all 384 cols (6 heads) per block, packed channel-major out.
// h2p word at [r*192 + ch*3 + k] = bf16 pair (head 2k lo, head 2k+1 hi).
// Also emits sal[r*SALS + head] = fp32 dot(h2_row_head, att_i[head]).
__global__ __launch_bounds__(256)
void k_gemm_h2(const float* __restrict__ A, const float* __restrict__ W,
               unsigned* __restrict__ h2p, const float* __restrict__ att,
               float* __restrict__ sal, int n) {
  __shared__ float At[64 * GSTRIDE];
  __shared__ float Wl[64 * GSTRIDE];
  const int t  = threadIdx.x;
  const int tx = t & 15;
  const int ty = t >> 4;
  const long row0 = (long)blockIdx.x * 64;
  const int c0 = 4 * tx;
  const int r0 = 4 * ty;

  // A tile load (coalesced) + transpose into At
  #pragma unroll
  for (int i = 0; i < 4; ++i) {
    int r = ty + 16 * i;
    long gr = row0 + r; if (gr >= n) gr = n - 1;
    float4 av = *(const float4*)&A[gr * 64 + 4 * tx];
    At[(4 * tx + 0) * GSTRIDE + r] = av.x;
    At[(4 * tx + 1) * GSTRIDE + r] = av.y;
    At[(4 * tx + 2) * GSTRIDE + r] = av.z;
    At[(4 * tx + 3) * GSTRIDE + r] = av.w;
  }
  // prefetch W tile for head 0 into registers
  float4 wr[4];
  #pragma unroll
  for (int i = 0; i < 4; ++i)
    wr[i] = *(const float4*)&W[(long)(ty + 16 * i) * 384 + 4 * tx];

  float4 acc[6][4];
  #pragma unroll
  for (int h = 0; h < 6; ++h)
    #pragma unroll
    for (int i = 0; i < 4; ++i) acc[h][i] = make_float4(0.f, 0.f, 0.f, 0.f);

  #pragma unroll
  for (int head = 0; head < 6; ++head) {
    // commit prefetched W tile to LDS
    #pragma unroll
    for (int i = 0; i < 4; ++i)
      *(float4*)&Wl[(ty + 16 * i) * GSTRIDE + 4 * tx] = wr[i];
    __syncthreads();
    // prefetch next head's W tile (overlaps with k-loop)
    if (head < 5) {
      #pragma unroll
      for (int i = 0; i < 4; ++i)
        wr[i] = *(const float4*)&W[(long)(ty + 16 * i) * 384 + (head + 1) * 64 + 4 * tx];
    }
    #pragma unroll 16
    for (int k = 0; k < 64; ++k) {
      float4 av = *(const float4*)&At[k * GSTRIDE + r0];
      float4 wv = *(const float4*)&Wl[k * GSTRIDE + c0];
      acc[head][0].x = fmaf(av.x, wv.x, acc[head][0].x);
      acc[head][0].y = fmaf(av.x, wv.y, acc[head][0].y);
      acc[head][0].z = fmaf(av.x, wv.z, acc[head][0].z);
      acc[head][0].w = fmaf(av.x, wv.w, acc[head][0].w);
      acc[head][1].x = fmaf(av.y, wv.x, acc[head][1].x);
      acc[head][1].y = fmaf(av.y, wv.y, acc[head][1].y);
      acc[head][1].z = fmaf(av.y, wv.z, acc[head][1].z);
      acc[head][1].w = fmaf(av.y, wv.w, acc[head][1].w);
      acc[head][2].x = fmaf(av.z, wv.x, acc[head][2].x);
      acc[head][2].y = fmaf(av.z, wv.y, acc[head][2].y);
      acc[head][2].z = fmaf(av.z, wv.z, acc[head][2].z);
      acc[head][2].w = fmaf(av.z, wv.w, acc[head][2].w);
      acc[head][3].x = fmaf(av.w, wv.x, acc[head][3].x);
      acc[head][3].y = fmaf(av.w, wv.y, acc[head][3].y);
      acc[head][3].z = fmaf(av.w, wv.z, acc[head][3].z);
      acc[head][3].w = fmaf(av.w, wv.w, acc[head][3].w);
    }
    __syncthreads();
  }

  // packed channel-major stores: per row, 12 contiguous dwords = 3x uint4
  #pragma unroll
  for (int i = 0; i < 4; ++i) {
    long gr = row0 + r0 + i;
    if (gr < n) {
      uint4 u0, u1, u2;
      u0.x = packbf(acc[0][i].x, acc[1][i].x);
      u0.y = packbf(acc[2][i].x, acc[3][i].x);
      u0.z = packbf(acc[4][i].x, acc[5][i].x);
      u0.w = packbf(acc[0][i].y, acc[1][i].y);
      u1.x = packbf(acc[2][i].y, acc[3][i].y);
      u1.y = packbf(acc[4][i].y, acc[5][i].y);
      u1.z = packbf(acc[0][i].z, acc[1][i].z);
      u1.w = packbf(acc[2][i].z, acc[3][i].z);
      u2.x = packbf(acc[4][i].z, acc[5][i].z);
      u2.y = packbf(acc[0][i].w, acc[1][i].w);
      u2.z = packbf(acc[2][i].w, acc[3][i].w);
      u2.w = packbf(acc[4][i].w, acc[5][i].w);
      unsigned* dst = &h2p[gr * 192 + c0 * 3];
      *(uint4*)(dst + 0) = u0;
      *(uint4*)(dst + 4) = u1;
      *(uint4*)(dst + 8) = u2;
    }
  }
  // sal epilogue: fp32 per-head dots, reduced across tx lanes
  #pragma unroll
  for (int head = 0; head < 6; ++head) {
    float a0 = att[head * 128 + c0 + 0], a1 = att[head * 128 + c0 + 1];
    float a2 = att[head * 128 + c0 + 2], a3 = att[head * 128 + c0 + 3];
    float p[4];
    #pragma unroll
    for (int i = 0; i < 4; ++i)
      p[i] = acc[head][i].x * a0 + acc[head][i].y * a1 +
             acc[head][i].z * a2 + acc[head][i].w * a3;
    #pragma unroll
    for (int m = 1; m < 16; m <<= 1) {
      #pragma unroll
      for (int i = 0; i < 4; ++i) p[i] += __shfl_xor(p[i], m);
    }
    if (tx == 0) {
      #pragma unroll
      for (int i = 0; i < 4; ++i) {
        long gr = row0 + r0 + i;
        if (gr < n) sal[gr * SALS + head] = p[i];
      }
    }
  }
}

// ---------- GCN aggregate via CSR (wave per node, lane = channel) ----------
__global__ __launch_bounds__(256)
void k_gcn_csr(const int* __restrict__ goff, const int* __restrict__ gcsr,
               const float* __restrict__ h, const float* __restrict__ dinv,
               const float* __restrict__ bg, float* __restrict__ xpj, int n) {
  const int lane = threadIdx.x & 63;
  const int d = blockIdx.x * 4 + (threadIdx.x >> 6);
  if (d >= n) return;
  const int o0 = goff[d], o1 = goff[d + 1];
  float acc = 0.f;
  int j = o0;
  for (; j + 1 < o1; j += 2) {
    int s0 = gcsr[j], s1 = gcsr[j + 1];
    float f0 = h[(long)s0 * 64 + lane], f1 = h[(long)s1 * 64 + lane];
    acc = fmaf(f0, dinv[s0], acc);
    acc = fmaf(f1, dinv[s1], acc);
  }
  if (j < o1) { int s0 = gcsr[j]; acc = fmaf(h[(long)s0 * 64 + lane], dinv[s0], acc); }
  float di = dinv[d];
  xpj[(long)d * 64 + lane] = bg[lane] + di * acc + h[(long)d * 64 + lane] * di * di;
}

// ---------- fused attention mega-kernel (wave per node) ----------
// h2p: channel-major packed bf16 pairs — uint k of row s at [s*192 + lane*3 + k]
// holds heads (2k, 2k+1) of channel `lane`.
__global__ __launch_bounds__(256)
void k_mega(const int* __restrict__ soff, const int* __restrict__ scsr,
            const unsigned* __restrict__ h2p, const float* __restrict__ sal,
            const float* __restrict__ att, float* __restrict__ xm, int n) {
  const int lane = threadIdx.x & 63;
  const int d = blockIdx.x * 4 + (threadIdx.x >> 6);
  if (d >= n) return;
  const int o0 = soff[d], o1 = soff[d + 1];
  const int deg = o1 - o0;

  // ---- pass 1: per-channel hmax + register cache of first DCACHE rows ----
  unsigned ck0[DCACHE], ck1[DCACHE], ck2[DCACHE];
  float hm[NH];
  #pragma unroll
  for (int h = 0; h < NH; ++h) hm[h] = -INFINITY;
  #pragma unroll
  for (int idx = 0; idx < DCACHE; ++idx) {
    unsigned u0 = 0, u1 = 0, u2 = 0;
    if (idx < deg) {
      long s = scsr[o0 + idx];
      const unsigned* rp = &h2p[s * 192 + lane * 3];
      u0 = rp[0]; u1 = rp[1]; u2 = rp[2];
      hm[0] = fmaxf(hm[0], bflo(u0)); hm[1] = fmaxf(hm[1], bfhi(u0));
      hm[2] = fmaxf(hm[2], bflo(u1)); hm[3] = fmaxf(hm[3], bfhi(u1));
      hm[4] = fmaxf(hm[4], bflo(u2)); hm[5] = fmaxf(hm[5], bfhi(u2));
    }
    ck0[idx] = u0; ck1[idx] = u1; ck2[idx] = u2;
  }
  for (int j = o0 + DCACHE; j < o1; ++j) {
    long s = scsr[j];
    const unsigned* rp = &h2p[s * 192 + lane * 3];
    unsigned u0 = rp[0], u1 = rp[1], u2 = rp[2];
    hm[0] = fmaxf(hm[0], bflo(u0)); hm[1] = fmaxf(hm[1], bfhi(u0));
    hm[2] = fmaxf(hm[2], bflo(u1)); hm[3] = fmaxf(hm[3], bfhi(u1));
    hm[4] = fmaxf(hm[4], bflo(u2)); hm[5] = fmaxf(hm[5], bfhi(u2));
  }

  float dal[NH];
  #pragma unroll
  for (int h = 0; h < NH; ++h)
    dal[h] = wave_sum64(hm[h] * att[h * 128 + 64 + lane]);

  float acc[NH], den[NH];
  #pragma unroll
  for (int h = 0; h < NH; ++h) acc[h] = 0.f;

  if (deg <= 64) {
    // ---- fast path: lane = edge softmax, all in one shot ----
    const bool act = lane < deg;
    int sE = 0;
    float4 sA = make_float4(0, 0, 0, 0), sB = sA;
    if (act) {
      sE = scsr[o0 + lane];
      const float4* sp = (const float4*)&sal[(long)sE * SALS];
      sA = sp[0]; sB = sp[1];
    }
    float svv[NH] = {sA.x, sA.y, sA.z, sA.w, sB.x, sB.y};
    float e6[NH];
    #pragma unroll
    for (int h = 0; h < NH; ++h) {
      float al = svv[h] + dal[h];
      al = (al >= 0.f) ? al : NEG_SLOPE * al;
      float a = act ? al : -INFINITY;
      float mx = wave_max64(a);
      e6[h] = act ? expf(a - mx) : 0.f;
      den[h] = wave_sum64(e6[h]);
    }
    // aggregate cached rows
    #pragma unroll
    for (int idx = 0; idx < DCACHE; ++idx) {
      if (idx < deg) {
        float w0 = __shfl(e6[0], idx), w1 = __shfl(e6[1], idx);
        float w2 = __shfl(e6[2], idx), w3 = __shfl(e6[3], idx);
        float w4 = __shfl(e6[4], idx), w5 = __shfl(e6[5], idx);
        acc[0] = fmaf(bflo(ck0[idx]), w0, acc[0]);
        acc[1] = fmaf(bfhi(ck0[idx]), w1, acc[1]);
        acc[2] = fmaf(bflo(ck1[idx]), w2, acc[2]);
        acc[3] = fmaf(bfhi(ck1[idx]), w3, acc[3]);
        acc[4] = fmaf(bflo(ck2[idx]), w4, acc[4]);
        acc[5] = fmaf(bfhi(ck2[idx]), w5, acc[5]);
      }
    }
    // overflow edges (DCACHE < deg <= 64): re-read rows
    for (int j = o0 + DCACHE; j < o1; ++j) {
      int ii = j - o0;
      long s = scsr[j];
      const unsigned* rp = &h2p[s * 192 + lane * 3];
      unsigned u0 = rp[0], u1 = rp[1], u2 = rp[2];
      float w0 = __shfl(e6[0], ii), w1 = __shfl(e6[1], ii);
      float w2 = __shfl(e6[2], ii), w3 = __shfl(e6[3], ii);
      float w4 = __shfl(e6[4], ii), w5 = __shfl(e6[5], ii);
      acc[0] = fmaf(bflo(u0), w0, acc[0]);
      acc[1] = fmaf(bfhi(u0), w1, acc[1]);
      acc[2] = fmaf(bflo(u1), w2, acc[2]);
      acc[3] = fmaf(bfhi(u1), w3, acc[3]);
      acc[4] = fmaf(bflo(u2), w4, acc[4]);
      acc[5] = fmaf(bfhi(u2), w5, acc[5]);
    }
  } else {
    // ---- slow path (deg > 64): base-block loops, no cache ----
    float mx[NH];
    #pragma unroll
    for (int h = 0; h < NH; ++h) { mx[h] = -INFINITY; den[h] = 0.f; }
    for (int base = o0; base < o1; base += 64) {
      int j = base + lane;
      float a6[NH];
      if (j < o1) {
        long s = scsr[j];
        const float4* sp = (const float4*)&sal[s * SALS];
        float4 sA = sp[0], sB = sp[1];
        float svv[NH] = {sA.x, sA.y, sA.z, sA.w, sB.x, sB.y};
        #pragma unroll
        for (int h = 0; h < NH; ++h) {
          float al = svv[h] + dal[h];
          a6[h] = (al >= 0.f) ? al : NEG_SLOPE * al;
        }
      } else {
        #pragma unroll
        for (int h = 0; h < NH; ++h) a6[h] = -INFINITY;
      }
      #pragma unroll
      for (int h = 0; h < NH; ++h) mx[h] = fmaxf(mx[h], wave_max64(a6[h]));
    }
    for (int base = o0; base < o1; base += 64) {
      int cs = o1 - base; if (cs > 64) cs = 64;
      int j = base + lane;
      float e6[NH]; int s = 0;
      if (j < o1) {
        s = scsr[j];
        const float4* sp = (const float4*)&sal[(long)s * SALS];
        float4 sA = sp[0], sB = sp[1];
        float svv[NH] = {sA.x, sA.y, sA.z, sA.w, sB.x, sB.y};
        #pragma unroll
        for (int h = 0; h < NH; ++h) {
          float al = svv[h] + dal[h];
          al = (al >= 0.f) ? al : NEG_SLOPE * al;
          e6[h] = expf(al - mx[h]);
        }
      } else {
        #pragma unroll
        for (int h = 0; h < NH; ++h) e6[h] = 0.f;
      }
      #pragma unroll
      for (int h = 0; h < NH; ++h) den[h] += wave_sum64(e6[h]);
      for (int jj = 0; jj < cs; ++jj) {
        int sj = __shfl(s, jj);
        const unsigned* rp = &h2p[(long)sj * 192 + lane * 3];
        unsigned u0 = rp[0], u1 = rp[1], u2 = rp[2];
        float w0 = __shfl(e6[0], jj), w1 = __shfl(e6[1], jj);
        float w2 = __shfl(e6[2], jj), w3 = __shfl(e6[3], jj);
        float w4 = __shfl(e6[4], jj), w5 = __shfl(e6[5], jj);
        acc[0] = fmaf(bflo(u0), w0, acc[0]);
        acc[1] = fmaf(bfhi(u0), w1, acc[1]);
        acc[2] = fmaf(bflo(u1), w2, acc[2]);
        acc[3] = fmaf(bfhi(u1), w3, acc[3]);
        acc[4] = fmaf(bflo(u2), w4, acc[4]);
        acc[5] = fmaf(bfhi(u2), w5, acc[5]);
      }
    }
  }

  float o = 0.f;
  #pragma unroll
  for (int h = 0; h < NH; ++h) o += acc[h] / den[h];
  xm[(long)d * 64 + lane] = o * (1.0f / NH);
}

// fitness[d] = sigmoid(bsc[d] * sum_j dot(an[s_j], an[d]))  (wave per node, bf16 an)
__global__ __launch_bounds__(256)
void k_cosout(const int* __restrict__ soff, const int* __restrict__ scsr,
              const unsigned short* __restrict__ an, const float* __restrict__ bsc,
              float* __restrict__ out, int n) {
  const int lane = threadIdx.x & 63;
  const int d = blockIdx.x * 4 + (threadIdx.x >> 6);
  if (d >= n) return;
  const int o0 = soff[d], o1 = soff[d + 1];
  float ad = bf2f(an[(long)d * 64 + lane]);
  float cl = 0.f;
  int j = o0;
  for (; j + 1 < o1; j += 2) {
    int s0 = scsr[j], s1 = scsr[j + 1];
    float f0 = bf2f(an[(long)s0 * 64 + lane]);
    float f1 = bf2f(an[(long)s1 * 64 + lane]);
    cl = fmaf(ad, f0, cl);
    cl = fmaf(ad, f1, cl);
  }
  if (j < o1) { int s0 = scsr[j]; cl = fmaf(ad, bf2f(an[(long)s0 * 64 + lane]), cl); }
  float cs = wave_sum64(cl);
  if (lane == 0) out[d] = 1.0f / (1.0f + expf(-bsc[d] * cs));
}

// ---------- launcher ----------
static inline unsigned gsblocks(long total) {
  long b = (total + TPB - 1) / TPB;
  if (b > 131072) b = 131072;
  return (unsigned)b;
}

extern "C" void kernel_launch(void* const* d_in, const int* in_sizes, int n_in,
                              void* d_out, int out_size, void* d_ws, size_t ws_size,
                              hipStream_t stream) {
  const float* x   = (const float*)d_in[0];
  const float* Wg  = (const float*)d_in[1];
  const float* bg  = (const float*)d_in[2];
  const float* Wt  = (const float*)d_in[3];
  const float* att = (const float*)d_in[4];
  const float* W1  = (const float*)d_in[5];
  const float* W2  = (const float*)d_in[6];
  const float* b2  = (const float*)d_in[7];
  const int* src   = (const int*)d_in[8];
  const int* dst   = (const int*)d_in[9];
  const int* ssrc  = (const int*)d_in[10];
  const int* sdst  = (const int*)d_in[11];

  const long n   = in_sizes[0] / 64;   // 50000
  const long en  = in_sizes[8];        // E + N
  const long sen = in_sizes[10];       // N + E
  const int  nb  = (int)((n + 2047) / 2048);

  char* base = (char*)d_ws;
  size_t off = 0;
  auto alloc = [&](size_t bytes) -> void* {
    void* p = base + off;
    off += (bytes + 255) & ~(size_t)255;
    return p;
  };
  int*   gcnt = (int*)alloc(n * 4);
  int*   scnt = (int*)alloc(n * 4);   // contiguous with gcnt (one memset)
  int*   goff = (int*)alloc((n + 1) * 4);
  int*   soff = (int*)alloc((n + 1) * 4);
  int*   gcur = (int*)alloc(n * 4);
  int*   scur = (int*)alloc(n * 4);
  int*   gcsr = (int*)alloc(en * 4);
  int*   scsr = (int*)alloc(sen * 4);
  int*   bsum = (int*)alloc(2 * (size_t)nb * 4);
  float* dinv = (float*)alloc(n * 4);
  float* h    = (float*)alloc(n * 64 * 4);            // later: xm
  float* xpj  = (float*)alloc(n * 64 * 4);            // later: anorm (bf16)
  unsigned* h2p = (unsigned*)alloc(n * 192 * 4);      // channel-major bf16 pairs
  float* sal  = (float*)alloc(n * SALS * 4);
  float* bsc  = (float*)alloc(n * 4);
  float* xm   = h;                                    // alias
  unsigned short* anorm = (unsigned short*)xpj;       // alias
  float* out  = (float*)d_out;

  const unsigned rowblk  = (unsigned)((n + 63) / 64);
  const unsigned nodeblk = (unsigned)((n + 3) / 4);

  // ---- CSR build (both graphs) + dinv ----
  hipMemsetAsync(gcnt, 0, (size_t)((char*)scnt - (char*)gcnt) + n * 4, stream);
  k_cnt<<<gsblocks(en), TPB, 0, stream>>>(dst, sdst, gcnt, scnt, en, sen);
  k_scanA<<<2 * nb, 1024, 0, stream>>>(gcnt, scnt, bsum, dinv, (int)n, nb);
  k_scanB<<<1, 64, 0, stream>>>(bsum, nb);
  k_scanC<<<2 * nb, 1024, 0, stream>>>(gcnt, goff, gcur, scnt, soff, scur,
                                       bsum, (int)n, nb);
  k_scatter<<<gsblocks(en), TPB, 0, stream>>>(src, dst, ssrc, sdst,
                                              gcur, gcsr, scur, scsr, en, sen);

  // ---- h = x @ W_gcn (fp32) ----
  { dim3 g(rowblk, 1);
    k_gemm64v3<0><<<g, 256, 0, stream>>>(x, Wg, h, nullptr,
                                         nullptr, nullptr, nullptr, (int)n, 64); }

  // ---- xpj = GCN(h) via CSR ----
  k_gcn_csr<<<nodeblk, 256, 0, stream>>>(goff, gcsr, h, dinv, bg, xpj, (int)n);

  // ---- h2 = xpj @ weight (bf16 channel-major packed) + fused sal ----
  k_gemm_h2<<<rowblk, 256, 0, stream>>>(xpj, Wt, h2p, att, sal, (int)n);

  // ---- fused attention -> xm (aliases h) ----
  k_mega<<<nodeblk, 256, 0, stream>>>(soff, scsr, h2p, sal, att, xm, (int)n);

  // ---- a = normalize(xm @ W1) (bf16, aliases xpj) + bsc, fused epilogue ----
  { dim3 g(rowblk, 1);
    k_gemm64v3<2><<<g, 256, 0, stream>>>(xm, W1, nullptr, anorm,
                                         W2, b2, bsc, (int)n, 64); }

  // ---- cosine + sigmoid -> out ----
  k_cosout<<<nodeblk, 256, 0, stream>>>(soff, scsr, anorm, bsc, out, (int)n);
}